// Round 4
// baseline (281.097 us; speedup 1.0000x reference)
//
#include <hip/hip_runtime.h>
#include <cstdint>
#include <cstddef>

// Problem constants
#define Bc  4
#define Sc  2048
#define Dc  1024
#define Hc  16
#define DDc 64
#define Nc  256   // pooled length

typedef unsigned short u16;
typedef unsigned int   u32;
typedef __bf16 bf16_t;
typedef bf16_t bf16x8 __attribute__((ext_vector_type(8)));
typedef float  f32x4  __attribute__((ext_vector_type(4)));

__device__ __forceinline__ u16 f2bf(float x) {
    u32 u = __float_as_uint(x);
    return (u16)((u + 0x7FFFu + ((u >> 16) & 1u)) >> 16);   // RNE
}
__device__ __forceinline__ u32 pack2(float a, float b) {
    return (u32)f2bf(a) | ((u32)f2bf(b) << 16);
}
__device__ __forceinline__ uint2 pack4(float4 x) {
    return make_uint2(pack2(x.x, x.y), pack2(x.z, x.w));
}
__device__ __forceinline__ float bf2f(u16 x) {
    return __uint_as_float((u32)x << 16);
}
__device__ __forceinline__ float4 f4add(float4 a, float4 b) {
    return make_float4(a.x + b.x, a.y + b.y, a.z + b.z, a.w + b.w);
}
__device__ __forceinline__ float4 f4sub(float4 a, float4 b) {
    return make_float4(a.x - b.x, a.y - b.y, a.z - b.z, a.w - b.w);
}

// async global->LDS, 16B per lane
__device__ __forceinline__ void gload_lds16(const void* gp, void* lp) {
    __builtin_amdgcn_global_load_lds(
        reinterpret_cast<const __attribute__((address_space(1))) void*>(
            reinterpret_cast<uintptr_t>(gp)),
        reinterpret_cast<__attribute__((address_space(3))) void*>(
            reinterpret_cast<uintptr_t>(lp)),
        16, 0, 0);
}

// ------------- weight prep: transpose + per-section column scaling -------------
// z=0..2 (q,k,v): Wt3[z][n][k], k in [0,3072): section s = k/1024,
//   Wt3[z][n][s*1024+kk] = W_z[kk][n] * 0.125*nrm_z*ws_s(n)
//   ws_0 = w0+w1+w2, ws_1 = w1+w2, ws_2 = w2   (w* = conv weights of input z at channel n)
// z=3: plain transposed-cast of Wc into Wtc.
__global__ __launch_bounds__(256) void prep_wt3(
    const float* __restrict__ Wq, const float* __restrict__ Wk,
    const float* __restrict__ Wv, const float* __restrict__ Wc,
    const float* __restrict__ wcq, const float* __restrict__ wck,
    const float* __restrict__ wcv,
    u16* __restrict__ Wt3, u16* __restrict__ Wtc)
{
    __shared__ float T[64][65];
    const int z = blockIdx.z;
    const float* W = (z == 0) ? Wq : (z == 1) ? Wk : (z == 2) ? Wv : Wc;
    const int k0 = blockIdx.y * 64, n0 = blockIdx.x * 64;
    const int c = threadIdx.x & 63, r4 = threadIdx.x >> 6;
    #pragma unroll
    for (int i = 0; i < 16; ++i) {
        int r = i * 4 + r4;
        T[r][c] = W[(size_t)(k0 + r) * 1024 + n0 + c];
    }
    __syncthreads();
    if (z < 3) {
        const float* wc = (z == 0) ? wcq : (z == 1) ? wck : wcv;
        const float fs = 0.125f * ((z == 2) ? 1.0f : 0.35355339059327373f);
        u16* dst0 = Wt3 + (size_t)z * 3145728;
        #pragma unroll
        for (int i = 0; i < 16; ++i) {
            int r = i * 4 + r4;
            int n = n0 + r;
            float w0 = wc[n], w1 = wc[1024 + n], w2 = wc[2048 + n];
            float s2 = fs * w2, s1 = s2 + fs * w1, s0 = s1 + fs * w0;
            float x = T[c][r];
            u16* dst = dst0 + (size_t)n * 3072 + k0 + c;
            dst[0]    = f2bf(x * s0);
            dst[1024] = f2bf(x * s1);
            dst[2048] = f2bf(x * s2);
        }
    } else {
        #pragma unroll
        for (int i = 0; i < 16; ++i) {
            int r = i * 4 + r4;
            Wtc[(size_t)(n0 + r) * 1024 + k0 + c] = f2bf(T[c][r]);
        }
    }
}

// ------------- bias table: biasT[z][j][c], j = min(t,2) -------------
__global__ __launch_bounds__(256) void prep_bias(
    const float* __restrict__ wcq, const float* __restrict__ wck, const float* __restrict__ wcv,
    const float* __restrict__ bcq, const float* __restrict__ bck, const float* __restrict__ bcv,
    const float* __restrict__ bq,  const float* __restrict__ bk,  const float* __restrict__ bv,
    float* __restrict__ biasT)
{
    int gid = blockIdx.x * 256 + threadIdx.x;   // over 3*1024
    int c = gid & 1023, z = gid >> 10;
    const float* wc    = (z == 0) ? wcq : (z == 1) ? wck : wcv;
    const float* bconv = (z == 0) ? bcq : (z == 1) ? bck : bcv;
    const float* bl    = (z == 0) ? bq  : (z == 1) ? bk  : bv;
    const float nrm = (z == 2) ? 1.0f : 0.35355339059327373f;
    float w0 = wc[c], w1 = wc[1024 + c], w2 = wc[2048 + c];
    float bc_ = bconv[c], bl_ = bl[c];
    float* dst = biasT + (size_t)z * 3072 + c;
    dst[0]    = 0.125f * (bc_ + nrm * bl_ * w2);
    dst[1024] = 0.125f * (8.f * bc_ + nrm * bl_ * (7.f * w0 + 8.f * w1 + 8.f * w2));
    dst[2048] = 0.125f * (8.f * bc_ + nrm * bl_ * 8.f * (w0 + w1 + w2));
}

// ------------- staging: differenced sections, K-concatenated -------------
// Thread t loads 10 contiguous rows [8t-9 .. 8t] (one float4 column slice):
//   A0[t] = sum rows 8t-9..8t-2 (r0..r7)   (window sum)
//   B1[t] = r8 - r0 = x[8t-1] - x[8t-9]    (so B1@W = Y1[t]-Y1[t-1])
//   B2[t] = r9 - r1 = x[8t]   - x[8t-8]
// Output A3[z][row=b*256+t][sec*1024+c] bf16, row stride 3072.
__global__ __launch_bounds__(256) void stage_kernel(
    const float* __restrict__ q, const float* __restrict__ k,
    const float* __restrict__ v, u16* __restrict__ A3)
{
    int gid = blockIdx.x * 256 + threadIdx.x;       // over 3 * 2^18 float4-groups
    int c4 = gid & 255, t = (gid >> 8) & 255, b = (gid >> 16) & 3, inp = gid >> 18;
    const float* src = (inp == 0) ? q : (inp == 1) ? k : v;
    const float4* Xb = (const float4*)(src + (size_t)b * Sc * Dc) + c4;
    const float4* Xr = Xb + ((ptrdiff_t)(t << 3) - 9) * 256;   // row 8t-9

    float4 r[10];
    if (t >= 2) {
        #pragma unroll
        for (int i = 0; i < 10; ++i) r[i] = Xr[(ptrdiff_t)i * 256];
    } else if (t == 1) {
        r[0] = make_float4(0.f, 0.f, 0.f, 0.f);
        #pragma unroll
        for (int i = 1; i < 10; ++i) r[i] = Xr[(ptrdiff_t)i * 256];
    } else {
        #pragma unroll
        for (int i = 0; i < 9; ++i) r[i] = make_float4(0.f, 0.f, 0.f, 0.f);
        r[9] = Xr[(ptrdiff_t)9 * 256];
    }

    float4 A0 = f4add(f4add(f4add(r[0], r[1]), f4add(r[2], r[3])),
                      f4add(f4add(r[4], r[5]), f4add(r[6], r[7])));
    float4 B1 = f4sub(r[8], r[0]);
    float4 B2 = f4sub(r[9], r[1]);

    size_t s0 = (size_t)inp * 3145728 + (size_t)(b * 256 + t) * 3072 + c4 * 4;
    *(uint2*)(A3 + s0)        = pack4(A0);
    *(uint2*)(A3 + s0 + 1024) = pack4(B1);
    *(uint2*)(A3 + s0 + 2048) = pack4(B2);
}

// ------------- fused QKV GEMM: [1024 x 3072] @ Wt3_z^T + biasT -> qb/kb/vt -------------
// 64x128 tiles, grid (8 n, 16 m, 3 z) = 384 blocks.
__global__ __launch_bounds__(256) void gemm_qkv(
    const u16* __restrict__ A3, const u16* __restrict__ Wt3,
    const float* __restrict__ biasT,
    u16* __restrict__ qb, u16* __restrict__ kb, u16* __restrict__ vt)
{
    __shared__ __align__(16) u16 As[64 * 32];
    __shared__ __align__(16) u16 Bs[128 * 32];

    const int tid  = threadIdx.x;
    const int lane = tid & 63;
    const int wv   = tid >> 6;
    const int z    = blockIdx.z;
    const int m0   = blockIdx.y * 64;
    const int n0   = blockIdx.x * 128;

    const int wm   = (wv & 1) * 32;
    const int wn   = (wv >> 1) * 64;
    const int mi   = lane & 15;
    const int quad = lane >> 4;

    const char* Ab = (const char*)(A3  + (size_t)z * 3145728);
    const char* Bb = (const char*)(Wt3 + (size_t)z * 3145728);

    f32x4 acc[2][4];
    #pragma unroll
    for (int i = 0; i < 2; ++i)
        #pragma unroll
        for (int j = 0; j < 4; ++j)
            acc[i][j] = (f32x4){0.f, 0.f, 0.f, 0.f};

    const int ra0 = tid >> 2, cb = (tid & 3) * 16;
    char* AsB = (char*)As;
    char* BsB = (char*)Bs;

    for (int k0 = 0; k0 < 3072; k0 += 32) {
        const size_t kb = (size_t)k0 * 2;
        gload_lds16(Ab + (size_t)(m0 + ra0)      * 6144 + kb + cb, AsB + wv * 1024);
        gload_lds16(Bb + (size_t)(n0 + ra0)      * 6144 + kb + cb, BsB + wv * 1024);
        gload_lds16(Bb + (size_t)(n0 + 64 + ra0) * 6144 + kb + cb, BsB + 4096 + wv * 1024);
        __syncthreads();

        bf16x8 af[2], bfr[4];
        #pragma unroll
        for (int i = 0; i < 2; ++i)
            af[i] = *reinterpret_cast<const bf16x8*>(&As[(wm + i * 16 + mi) * 32 + quad * 8]);
        #pragma unroll
        for (int j = 0; j < 4; ++j)
            bfr[j] = *reinterpret_cast<const bf16x8*>(&Bs[(wn + j * 16 + mi) * 32 + quad * 8]);

        #pragma unroll
        for (int i = 0; i < 2; ++i)
            #pragma unroll
            for (int j = 0; j < 4; ++j)
                acc[i][j] = __builtin_amdgcn_mfma_f32_16x16x32_bf16(af[i], bfr[j], acc[i][j], 0, 0, 0);

        __syncthreads();
    }

    const float* bT = biasT + (size_t)z * 3072;
    if (z == 2) {
        #pragma unroll
        for (int j = 0; j < 4; ++j) {
            const int col = n0 + wn + j * 16 + mi;
            const int h = col >> 6, d = col & 63;
            #pragma unroll
            for (int i = 0; i < 2; ++i) {
                const int row = m0 + wm + i * 16 + quad * 4;
                const int b = row >> 8, t0 = row & 255;
                const int bh = b * 16 + h;
                u16 w[4];
                #pragma unroll
                for (int r = 0; r < 4; ++r) {
                    int t = t0 + r;
                    w[r] = f2bf(acc[i][j][r] + bT[(t < 2 ? t : 2) * 1024 + col]);
                }
                *(uint2*)(vt + (size_t)bh * 20480 + (size_t)d * 256 + t0) =
                    make_uint2((u32)w[0] | ((u32)w[1] << 16), (u32)w[2] | ((u32)w[3] << 16));
            }
        }
    } else {
        u16* dst = z ? kb : qb;
        #pragma unroll
        for (int j = 0; j < 4; ++j) {
            const int col = n0 + wn + j * 16 + mi;
            const int h = col >> 6, d = col & 63;
            #pragma unroll
            for (int i = 0; i < 2; ++i) {
                const int row = m0 + wm + i * 16 + quad * 4;
                const int b = row >> 8;
                const int bh = b * 16 + h;
                #pragma unroll
                for (int r = 0; r < 4; ++r) {
                    int t = (row & 255) + r;
                    dst[(((size_t)bh * 256 + t) << 6) + d] =
                        f2bf(acc[i][j][r] + bT[(t < 2 ? t : 2) * 1024 + col]);
                }
            }
        }
    }
}

// ------------- pad V^T rows 64..79: row 64 = 1.0 (softmax-l trick), rows 65..79 = 0 -------------
__global__ __launch_bounds__(256) void vpad_kernel(u16* __restrict__ vt)
{
    const int bh = blockIdx.x;
    const int tid = threadIdx.x;
    const int rr = tid >> 4;            // 0..15 (row 64+rr)
    const int c0 = (tid & 15) * 16;     // 16 u16 per thread
    u32 fill = (rr == 0) ? 0x3F803F80u : 0u;
    uint4 val = make_uint4(fill, fill, fill, fill);
    uint4* p = (uint4*)(vt + (size_t)bh * 80 * 256 + (size_t)(64 + rr) * 256 + c0);
    p[0] = val;
    p[1] = val;
}

// ---------------- MFMA causal attention ----------------
// One block per (qt, bh): 1 wave (64 threads), 256 blocks total (was 64 blocks
// x 4 waves: only 64 of 256 CUs busy). Wave owns q-rows [64qt,64qt+64),
// loops key-tiles 0..qt. Max-free softmax; l via ones-row of V^T.
__global__ __launch_bounds__(64) void attn_mfma(
    const u16* __restrict__ qb, const u16* __restrict__ kb,
    const u16* __restrict__ vt, float* __restrict__ ao)
{
    __shared__ __align__(16) u16 P[64 * 72];    // stride 72 u16: 2-way banks only
    const int qt   = blockIdx.x;
    const int bh   = blockIdx.y;
    const int lane = threadIdx.x;
    const int mi   = lane & 15;
    const int quad = lane >> 4;

    const u16* Qb = qb + (((size_t)bh * 256 + qt * 64) << 6);
    const u16* Kb = kb + ((size_t)bh << 14);        // *256*64
    const u16* Vt = vt + (size_t)bh * 80 * 256;

    // Q fragments (persist across key tiles): A[m=mi][k=quad*8+j]
    bf16x8 qf[4][2];
    #pragma unroll
    for (int it = 0; it < 4; ++it)
        #pragma unroll
        for (int kc = 0; kc < 2; ++kc)
            qf[it][kc] = *(const bf16x8*)(Qb + ((it * 16 + mi) << 6) + kc * 32 + quad * 8);

    f32x4 o[4][5];
    #pragma unroll
    for (int it = 0; it < 4; ++it)
        #pragma unroll
        for (int jn = 0; jn < 5; ++jn)
            o[it][jn] = (f32x4){0.f, 0.f, 0.f, 0.f};

    for (int kt = 0; kt <= qt; ++kt) {
        // ---- S = Q @ K^T over this 64-key tile ----
        bf16x8 kf[4][2];
        #pragma unroll
        for (int jt = 0; jt < 4; ++jt)
            #pragma unroll
            for (int kc = 0; kc < 2; ++kc)
                kf[jt][kc] = *(const bf16x8*)(Kb + ((kt * 64 + jt * 16 + mi) << 6) + kc * 32 + quad * 8);

        f32x4 s[4][4];
        #pragma unroll
        for (int it = 0; it < 4; ++it)
            #pragma unroll
            for (int jt = 0; jt < 4; ++jt)
                s[it][jt] = (f32x4){0.f, 0.f, 0.f, 0.f};
        #pragma unroll
        for (int kc = 0; kc < 2; ++kc)
            #pragma unroll
            for (int it = 0; it < 4; ++it)
                #pragma unroll
                for (int jt = 0; jt < 4; ++jt)
                    s[it][jt] = __builtin_amdgcn_mfma_f32_16x16x32_bf16(qf[it][kc], kf[jt][kc], s[it][jt], 0, 0, 0);

        // ---- mask (diagonal tile only) + exp -> P (bf16, LDS, [row][key] stride 72) ----
        const bool diag = (kt == qt);
        #pragma unroll
        for (int it = 0; it < 4; ++it)
            #pragma unroll
            for (int jt = 0; jt < 4; ++jt)
                #pragma unroll
                for (int r = 0; r < 4; ++r) {
                    int qrow = it * 16 + quad * 4 + r;
                    int kcol = jt * 16 + mi;
                    float e = __expf(s[it][jt][r]);
                    if (diag && kcol > qrow) e = 0.f;
                    P[qrow * 72 + kcol] = f2bf(e);
                }

        // ---- PV: o += P @ [V | 1]^T  (A-frags from LDS, B-frags from V^T global) ----
        bf16x8 pf[4][2];
        #pragma unroll
        for (int it = 0; it < 4; ++it)
            #pragma unroll
            for (int kc = 0; kc < 2; ++kc)
                pf[it][kc] = *(const bf16x8*)(P + (it * 16 + mi) * 72 + kc * 32 + quad * 8);

        bf16x8 vf[5][2];
        #pragma unroll
        for (int jn = 0; jn < 5; ++jn)
            #pragma unroll
            for (int kc = 0; kc < 2; ++kc)
                vf[jn][kc] = *(const bf16x8*)(Vt + (size_t)(jn * 16 + mi) * 256 + kt * 64 + kc * 32 + quad * 8);

        #pragma unroll
        for (int kc = 0; kc < 2; ++kc)
            #pragma unroll
            for (int it = 0; it < 4; ++it)
                #pragma unroll
                for (int jn = 0; jn < 5; ++jn)
                    o[it][jn] = __builtin_amdgcn_mfma_f32_16x16x32_bf16(pf[it][kc], vf[jn][kc], o[it][jn], 0, 0, 0);
    }

    // ---- epilogue: l sits in n-tile 4 (ones row of V^T), lanes mi==0; broadcast & divide ----
    #pragma unroll
    for (int it = 0; it < 4; ++it) {
        float inv[4];
        #pragma unroll
        for (int r = 0; r < 4; ++r) {
            float lv = __shfl(o[it][4][r], (lane & 48));   // from lane quad*16+0
            inv[r] = 1.0f / lv;
        }
        #pragma unroll
        for (int jn = 0; jn < 4; ++jn)
            #pragma unroll
            for (int r = 0; r < 4; ++r) {
                int row = qt * 64 + it * 16 + quad * 4 + r;
                ao[(((size_t)bh * 256 + row) << 6) + jn * 16 + mi] = o[it][jn][r] * inv[r];
            }
    }
}

// ---------------- up-dense (64x64) + head-merge into [B, n, D] (bf16 out) ----------------
__global__ __launch_bounds__(256) void updense_kernel(
    const float* __restrict__ ao, const float* __restrict__ Wup,
    const float* __restrict__ bup, u16* __restrict__ ms)
{
    __shared__ float Ws[64 * 64];
    __shared__ float rows[4 * 64];
    const int tid = threadIdx.x;

    #pragma unroll
    for (int i = 0; i < 4; ++i)
        ((float4*)Ws)[tid + 256 * i] = ((const float4*)Wup)[tid + 256 * i];
    rows[tid] = ao[(size_t)blockIdx.x * 256 + tid];
    __syncthreads();

    const int r = tid >> 6, dp = tid & 63;
    const int R = blockIdx.x * 4 + r;
    const int b = R >> 12;
    const int h = (R >> 8) & 15;
    const int m = R & 255;

    float acc = bup[dp];
    #pragma unroll
    for (int d = 0; d < 64; ++d)
        acc += rows[r * 64 + d] * Ws[d * 64 + dp];

    ms[((size_t)(b * Nc + m) << 10) + h * 64 + dp] = f2bf(acc);
}

// ------------- final dense: C = ms @ Wtc^T + bc, fp32 [1024][1024] into ws -------------
__global__ __launch_bounds__(256) void gemm_out(
    const u16* __restrict__ A, const u16* __restrict__ Bt,
    const float* __restrict__ bias, float* __restrict__ C)
{
    __shared__ __align__(16) u16 As[64 * 32];
    __shared__ __align__(16) u16 Bs[64 * 32];

    const int tid  = threadIdx.x;
    const int lane = tid & 63;
    const int wv   = tid >> 6;
    const int m0   = blockIdx.y * 64;
    const int n0   = blockIdx.x * 64;

    const int wm   = (wv >> 1) * 32;
    const int wn   = (wv & 1) * 32;
    const int mi   = lane & 15;
    const int quad = lane >> 4;

    f32x4 acc[2][2];
    #pragma unroll
    for (int i = 0; i < 2; ++i)
        #pragma unroll
        for (int j = 0; j < 2; ++j)
            acc[i][j] = (f32x4){0.f, 0.f, 0.f, 0.f};

    const char* Ab = (const char*)A;
    const char* Bb = (const char*)Bt;
    const int ra0 = tid >> 2, cb = (tid & 3) * 16;
    char* AsB = (char*)As;
    char* BsB = (char*)Bs;

    for (int k0 = 0; k0 < 1024; k0 += 32) {
        const size_t kb = (size_t)k0 * 2;
        gload_lds16(Ab + ((size_t)(m0 + ra0) << 11) + kb + cb, AsB + wv * 1024);
        gload_lds16(Bb + ((size_t)(n0 + ra0) << 11) + kb + cb, BsB + wv * 1024);
        __syncthreads();

        bf16x8 af[2], bfr[2];
        #pragma unroll
        for (int i = 0; i < 2; ++i)
            af[i] = *reinterpret_cast<const bf16x8*>(&As[(wm + i * 16 + mi) * 32 + quad * 8]);
        #pragma unroll
        for (int j = 0; j < 2; ++j)
            bfr[j] = *reinterpret_cast<const bf16x8*>(&Bs[(wn + j * 16 + mi) * 32 + quad * 8]);

        #pragma unroll
        for (int i = 0; i < 2; ++i)
            #pragma unroll
            for (int j = 0; j < 2; ++j)
                acc[i][j] = __builtin_amdgcn_mfma_f32_16x16x32_bf16(af[i], bfr[j], acc[i][j], 0, 0, 0);

        __syncthreads();
    }

    #pragma unroll
    for (int j = 0; j < 2; ++j) {
        const int col = n0 + wn + j * 16 + mi;
        const float bv = bias[col];
        #pragma unroll
        for (int i = 0; i < 2; ++i) {
            const int row = m0 + wm + i * 16 + quad * 4;
            #pragma unroll
            for (int r = 0; r < 4; ++r)
                C[(size_t)(row + r) * 1024 + col] = acc[i][j][r] + bv;
        }
    }
}

// ------------- upsample 8x: out[b, t, :] = C[b*256 + t/8, :], coalesced float4 -------------
__global__ __launch_bounds__(256) void upsample_kernel(
    const float* __restrict__ C, float* __restrict__ out)
{
    const float4* C4  = (const float4*)C;
    float4*       out4 = (float4*)out;
    int idx0 = blockIdx.x * 1024 + threadIdx.x;
    #pragma unroll
    for (int rep = 0; rep < 4; ++rep) {
        int o4   = idx0 + rep * 256;       // over 2^21 float4s
        int col4 = o4 & 255;
        int rowo = o4 >> 8;                // 0..8191 output row
        int b    = rowo >> 11;
        int tc   = (rowo & 2047) >> 3;     // pooled row
        out4[o4] = C4[(size_t)((b << 8) + tc) * 256 + col4];
    }
}

extern "C" void kernel_launch(void* const* d_in, const int* in_sizes, int n_in,
                              void* d_out, int out_size, void* d_ws, size_t ws_size,
                              hipStream_t stream) {
    const float* q   = (const float*)d_in[0];
    const float* k   = (const float*)d_in[1];
    const float* v   = (const float*)d_in[2];
    const float* Wq  = (const float*)d_in[3];
    const float* bq  = (const float*)d_in[4];
    const float* Wk  = (const float*)d_in[5];
    const float* bk  = (const float*)d_in[6];
    const float* Wv  = (const float*)d_in[7];
    const float* bv  = (const float*)d_in[8];
    const float* Wup = (const float*)d_in[9];
    const float* bup = (const float*)d_in[10];
    const float* Wc  = (const float*)d_in[11];
    const float* bc  = (const float*)d_in[12];
    const float* wcq = (const float*)d_in[13];
    const float* bcq = (const float*)d_in[14];
    const float* wck = (const float*)d_in[15];
    const float* bck = (const float*)d_in[16];
    const float* wcv = (const float*)d_in[17];
    const float* bcv = (const float*)d_in[18];

    // A3 staging (18.9 MB bf16 [3][1024][3072]) lives in d_out; upsample rewrites
    // all of d_out at the end.
    u16* A3 = (u16*)d_out;

    char* wsb = (char*)d_ws;
    // ws layout (bytes), total 34.1 MB:
    //   0        : Wt3  bf16 [3][1024 n][3072 k]  18,874,368
    //   18874368 : Wtc  bf16 [1024][1024]          2,097,152
    //   20971520 : biasT f32 [3][3][1024]             36,864
    //   21008384 : qb   bf16 [64*256][64]          2,097,152
    //   23105536 : kb   bf16 [64*256][64]          2,097,152
    //   25202688 : vt   bf16 [64][80][256]         2,621,440
    //   27824128 : ao   fp32 [64*256][64]          4,194,304  (reused as C fp32)
    //   32018432 : ms   bf16 [1024][1024]          2,097,152
    u16*   Wt3   = (u16*)wsb;
    u16*   Wtc   = (u16*)(wsb + 18874368);
    float* biasT = (float*)(wsb + 20971520);
    u16*   qb    = (u16*)(wsb + 21008384);
    u16*   kb    = (u16*)(wsb + 23105536);
    u16*   vt    = (u16*)(wsb + 25202688);
    float* ao    = (float*)(wsb + 27824128);
    u16*   ms    = (u16*)(wsb + 32018432);
    float* Cf    = ao;   // ao is dead after updense_kernel; reuse for final-dense C

    // 1. weight prep: scaled+transposed Wt3 (q,k,v) + plain Wtc
    prep_wt3<<<dim3(16, 16, 4), 256, 0, stream>>>(Wq, Wk, Wv, Wc, wcq, wck, wcv, Wt3, Wtc);
    // 1b. bias table
    prep_bias<<<12, 256, 0, stream>>>(wcq, wck, wcv, bcq, bck, bcv, bq, bk, bv, biasT);
    // 2. stage differenced sections (K-concatenated) into d_out
    stage_kernel<<<3072, 256, 0, stream>>>(q, k, v, A3);
    // 3. fused QKV GEMM (K=3072) writing qb/kb/vt directly (combine deleted)
    gemm_qkv<<<dim3(8, 16, 3), 256, 0, stream>>>(A3, Wt3, biasT, qb, kb, vt);
    // 3b. V^T ones/zero pad rows (softmax-l trick)
    vpad_kernel<<<64, 256, 0, stream>>>(vt);
    // 4. MFMA causal attention, 256 one-wave blocks (all CUs)
    attn_mfma<<<dim3(4, 64), 64, 0, stream>>>(qb, kb, vt, ao);
    // 5. up-dense + merge heads -> ms bf16 [B*n][D]
    updense_kernel<<<(Bc * Hc * Nc) / 4, 256, 0, stream>>>(ao, Wup, bup, ms);
    // 6. final dense -> C fp32 (256 blocks)
    gemm_out<<<dim3(16, 16), 256, 0, stream>>>(ms, Wtc, bc, Cf);
    // 7. 8x upsample broadcast, coalesced float4 writes
    upsample_kernel<<<2048, 256, 0, stream>>>(Cf, (float*)d_out);
}

// Round 5
// 257.051 us; speedup vs baseline: 1.0935x; 1.0935x over previous
//
#include <hip/hip_runtime.h>
#include <cstdint>
#include <cstddef>

// Problem constants
#define Bc  4
#define Sc  2048
#define Dc  1024
#define Hc  16
#define DDc 64
#define Nc  256   // pooled length

typedef unsigned short u16;
typedef unsigned int   u32;
typedef __bf16 bf16_t;
typedef bf16_t bf16x8 __attribute__((ext_vector_type(8)));
typedef float  f32x4  __attribute__((ext_vector_type(4)));

__device__ __forceinline__ u16 f2bf(float x) {
    u32 u = __float_as_uint(x);
    return (u16)((u + 0x7FFFu + ((u >> 16) & 1u)) >> 16);   // RNE
}
__device__ __forceinline__ u32 pack2(float a, float b) {
    return (u32)f2bf(a) | ((u32)f2bf(b) << 16);
}
__device__ __forceinline__ uint2 pack4(float4 x) {
    return make_uint2(pack2(x.x, x.y), pack2(x.z, x.w));
}
__device__ __forceinline__ float bf2f(u16 x) {
    return __uint_as_float((u32)x << 16);
}
__device__ __forceinline__ float4 f4add(float4 a, float4 b) {
    return make_float4(a.x + b.x, a.y + b.y, a.z + b.z, a.w + b.w);
}
__device__ __forceinline__ float4 f4sub(float4 a, float4 b) {
    return make_float4(a.x - b.x, a.y - b.y, a.z - b.z, a.w - b.w);
}

// async global->LDS, 16B per lane
__device__ __forceinline__ void gload_lds16(const void* gp, void* lp) {
    __builtin_amdgcn_global_load_lds(
        reinterpret_cast<const __attribute__((address_space(1))) void*>(
            reinterpret_cast<uintptr_t>(gp)),
        reinterpret_cast<__attribute__((address_space(3))) void*>(
            reinterpret_cast<uintptr_t>(lp)),
        16, 0, 0);
}

// ---- 1-wave GEMM building blocks (64x64 tile, BK=64, granule-swizzled LDS) ----
// Stage one 64-row x 128-byte K-slab into 8KB LDS. LDS slot (row r, granule g)
// receives global granule g ^ (r&7)  (8 granules of 16B per 128B row).
// Reader applies the same XOR -> bank-conflict-free, layout self-inverse.
__device__ __forceinline__ void stage64(const char* src, size_t kb, u16* lds,
                                        int lane, size_t rstride) {
    const int rowoff = lane >> 3;                       // 0..7
    const int srcg   = ((lane & 7) ^ (rowoff & 7)) * 16;
    const char* s0 = src + kb + (size_t)srcg;
    #pragma unroll
    for (int i = 0; i < 8; ++i)
        gload_lds16(s0 + (size_t)(8 * i + rowoff) * rstride,
                    (char*)lds + i * 1024);             // wave-uniform dest base
}

// Read 4x2 bf16x8 fragments (rows i*16+mi, K-halves kc) with the inverse XOR.
__device__ __forceinline__ void frag_read(const u16* lds, int mi, int quad,
                                          bf16x8 f[4][2]) {
    const int key = mi & 7;                             // (i*16+mi)&7 == mi&7
    #pragma unroll
    for (int i = 0; i < 4; ++i)
        #pragma unroll
        for (int kc = 0; kc < 2; ++kc) {
            int g = (kc * 4 + quad) ^ key;
            f[i][kc] = *(const bf16x8*)(lds + (i * 16 + mi) * 64 + g * 8);
        }
}

// ------------- weight prep: transpose + per-section column scaling -------------
// z=0..2 (q,k,v): Wt3[z][n][k], k in [0,3072): section s = k/1024,
//   Wt3[z][n][s*1024+kk] = W_z[kk][n] * 0.125*nrm_z*ws_s(n)
//   ws_0 = w0+w1+w2, ws_1 = w1+w2, ws_2 = w2   (w* = conv weights of input z at channel n)
// z=3: plain transposed-cast of Wc into Wtc.
__global__ __launch_bounds__(256) void prep_wt3(
    const float* __restrict__ Wq, const float* __restrict__ Wk,
    const float* __restrict__ Wv, const float* __restrict__ Wc,
    const float* __restrict__ wcq, const float* __restrict__ wck,
    const float* __restrict__ wcv,
    u16* __restrict__ Wt3, u16* __restrict__ Wtc)
{
    __shared__ float T[64][65];
    const int z = blockIdx.z;
    const float* W = (z == 0) ? Wq : (z == 1) ? Wk : (z == 2) ? Wv : Wc;
    const int k0 = blockIdx.y * 64, n0 = blockIdx.x * 64;
    const int c = threadIdx.x & 63, r4 = threadIdx.x >> 6;
    #pragma unroll
    for (int i = 0; i < 16; ++i) {
        int r = i * 4 + r4;
        T[r][c] = W[(size_t)(k0 + r) * 1024 + n0 + c];
    }
    __syncthreads();
    if (z < 3) {
        const float* wc = (z == 0) ? wcq : (z == 1) ? wck : wcv;
        const float fs = 0.125f * ((z == 2) ? 1.0f : 0.35355339059327373f);
        u16* dst0 = Wt3 + (size_t)z * 3145728;
        #pragma unroll
        for (int i = 0; i < 16; ++i) {
            int r = i * 4 + r4;
            int n = n0 + r;
            float w0 = wc[n], w1 = wc[1024 + n], w2 = wc[2048 + n];
            float s2 = fs * w2, s1 = s2 + fs * w1, s0 = s1 + fs * w0;
            float x = T[c][r];
            u16* dst = dst0 + (size_t)n * 3072 + k0 + c;
            dst[0]    = f2bf(x * s0);
            dst[1024] = f2bf(x * s1);
            dst[2048] = f2bf(x * s2);
        }
    } else {
        #pragma unroll
        for (int i = 0; i < 16; ++i) {
            int r = i * 4 + r4;
            Wtc[(size_t)(n0 + r) * 1024 + k0 + c] = f2bf(T[c][r]);
        }
    }
}

// ------------- bias table: biasT[z][j][c], j = min(t,2) -------------
__global__ __launch_bounds__(256) void prep_bias(
    const float* __restrict__ wcq, const float* __restrict__ wck, const float* __restrict__ wcv,
    const float* __restrict__ bcq, const float* __restrict__ bck, const float* __restrict__ bcv,
    const float* __restrict__ bq,  const float* __restrict__ bk,  const float* __restrict__ bv,
    float* __restrict__ biasT)
{
    int gid = blockIdx.x * 256 + threadIdx.x;   // over 3*1024
    int c = gid & 1023, z = gid >> 10;
    const float* wc    = (z == 0) ? wcq : (z == 1) ? wck : wcv;
    const float* bconv = (z == 0) ? bcq : (z == 1) ? bck : bcv;
    const float* bl    = (z == 0) ? bq  : (z == 1) ? bk  : bv;
    const float nrm = (z == 2) ? 1.0f : 0.35355339059327373f;
    float w0 = wc[c], w1 = wc[1024 + c], w2 = wc[2048 + c];
    float bc_ = bconv[c], bl_ = bl[c];
    float* dst = biasT + (size_t)z * 3072 + c;
    dst[0]    = 0.125f * (bc_ + nrm * bl_ * w2);
    dst[1024] = 0.125f * (8.f * bc_ + nrm * bl_ * (7.f * w0 + 8.f * w1 + 8.f * w2));
    dst[2048] = 0.125f * (8.f * bc_ + nrm * bl_ * 8.f * (w0 + w1 + w2));
}

// ------------- staging: differenced sections, K-concatenated -------------
// Thread t loads 10 contiguous rows [8t-9 .. 8t] (one float4 column slice):
//   A0[t] = sum rows 8t-9..8t-2 (r0..r7)   (window sum)
//   B1[t] = r8 - r0 = x[8t-1] - x[8t-9]    (so B1@W = Y1[t]-Y1[t-1])
//   B2[t] = r9 - r1 = x[8t]   - x[8t-8]
// Output A3[z][row=b*256+t][sec*1024+c] bf16, row stride 3072.
__global__ __launch_bounds__(256) void stage_kernel(
    const float* __restrict__ q, const float* __restrict__ k,
    const float* __restrict__ v, u16* __restrict__ A3)
{
    int gid = blockIdx.x * 256 + threadIdx.x;       // over 3 * 2^18 float4-groups
    int c4 = gid & 255, t = (gid >> 8) & 255, b = (gid >> 16) & 3, inp = gid >> 18;
    const float* src = (inp == 0) ? q : (inp == 1) ? k : v;
    const float4* Xb = (const float4*)(src + (size_t)b * Sc * Dc) + c4;
    const float4* Xr = Xb + ((ptrdiff_t)(t << 3) - 9) * 256;   // row 8t-9

    float4 r[10];
    if (t >= 2) {
        #pragma unroll
        for (int i = 0; i < 10; ++i) r[i] = Xr[(ptrdiff_t)i * 256];
    } else if (t == 1) {
        r[0] = make_float4(0.f, 0.f, 0.f, 0.f);
        #pragma unroll
        for (int i = 1; i < 10; ++i) r[i] = Xr[(ptrdiff_t)i * 256];
    } else {
        #pragma unroll
        for (int i = 0; i < 9; ++i) r[i] = make_float4(0.f, 0.f, 0.f, 0.f);
        r[9] = Xr[(ptrdiff_t)9 * 256];
    }

    float4 A0 = f4add(f4add(f4add(r[0], r[1]), f4add(r[2], r[3])),
                      f4add(f4add(r[4], r[5]), f4add(r[6], r[7])));
    float4 B1 = f4sub(r[8], r[0]);
    float4 B2 = f4sub(r[9], r[1]);

    size_t s0 = (size_t)inp * 3145728 + (size_t)(b * 256 + t) * 3072 + c4 * 4;
    *(uint2*)(A3 + s0)        = pack4(A0);
    *(uint2*)(A3 + s0 + 1024) = pack4(B1);
    *(uint2*)(A3 + s0 + 2048) = pack4(B2);
}

// ------------- fused QKV GEMM: [1024 x 3072] @ Wt3_z^T + biasT -> qb/kb/vt -------------
// 1-wave blocks, 64x64 tile, 4x4 acc (16 ds_reads feed 32 MFMAs), BK=64,
// double-buffered LDS with counted vmcnt(16) (never drained mid-loop), no barriers.
// Grid 768 = 16m x 16n x 3z, XCD-chunked bijective swizzle (768 = 8*96).
__global__ __launch_bounds__(64) void gemm_qkv(
    const u16* __restrict__ A3, const u16* __restrict__ Wt3,
    const float* __restrict__ biasT,
    u16* __restrict__ qb, u16* __restrict__ kb, u16* __restrict__ vt)
{
    __shared__ __align__(16) u16 S[2][2][4096];   // [buf][A|B][64*64]

    const int lane = threadIdx.x;
    const int mi   = lane & 15;
    const int quad = lane >> 4;

    const int bid = blockIdx.x;                   // 0..767
    const int wg  = (bid & 7) * 96 + (bid >> 3);  // bijective XCD chunking
    const int z   = wg >> 8;
    const int m0  = ((wg >> 4) & 15) * 64;
    const int n0  = (wg & 15) * 64;

    const char* Ab = (const char*)(A3  + (size_t)z * 3145728) + (size_t)m0 * 6144;
    const char* Bb = (const char*)(Wt3 + (size_t)z * 3145728) + (size_t)n0 * 6144;

    f32x4 acc[4][4];
    #pragma unroll
    for (int i = 0; i < 4; ++i)
        #pragma unroll
        for (int j = 0; j < 4; ++j)
            acc[i][j] = (f32x4){0.f, 0.f, 0.f, 0.f};

    stage64(Ab, 0, S[0][0], lane, 6144);
    stage64(Bb, 0, S[0][1], lane, 6144);

    #pragma unroll 1
    for (int t = 0; t < 48; ++t) {
        const int cur = t & 1;
        if (t < 47) {
            stage64(Ab, (size_t)(t + 1) * 128, S[cur ^ 1][0], lane, 6144);
            stage64(Bb, (size_t)(t + 1) * 128, S[cur ^ 1][1], lane, 6144);
            asm volatile("s_waitcnt vmcnt(16)" ::: "memory");   // cur's 16 done, next 16 in flight
        } else {
            asm volatile("s_waitcnt vmcnt(0)" ::: "memory");
        }
        __builtin_amdgcn_sched_barrier(0);

        bf16x8 af[4][2], bf[4][2];
        frag_read(S[cur][0], mi, quad, af);
        frag_read(S[cur][1], mi, quad, bf);

        #pragma unroll
        for (int kc = 0; kc < 2; ++kc)
            #pragma unroll
            for (int i = 0; i < 4; ++i)
                #pragma unroll
                for (int j = 0; j < 4; ++j)
                    acc[i][j] = __builtin_amdgcn_mfma_f32_16x16x32_bf16(af[i][kc], bf[j][kc], acc[i][j], 0, 0, 0);
    }

    const float* bT = biasT + (size_t)z * 3072;
    if (z == 2) {
        #pragma unroll
        for (int j = 0; j < 4; ++j) {
            const int col = n0 + j * 16 + mi;
            const int h = col >> 6, d = col & 63;
            #pragma unroll
            for (int i = 0; i < 4; ++i) {
                const int row = m0 + i * 16 + quad * 4;
                const int b = row >> 8, t0 = row & 255;
                const int bh = b * 16 + h;
                u16 w[4];
                #pragma unroll
                for (int r = 0; r < 4; ++r) {
                    int t = t0 + r;
                    w[r] = f2bf(acc[i][j][r] + bT[(t < 2 ? t : 2) * 1024 + col]);
                }
                *(uint2*)(vt + (size_t)bh * 20480 + (size_t)d * 256 + t0) =
                    make_uint2((u32)w[0] | ((u32)w[1] << 16), (u32)w[2] | ((u32)w[3] << 16));
            }
        }
    } else {
        u16* dst = z ? kb : qb;
        #pragma unroll
        for (int j = 0; j < 4; ++j) {
            const int col = n0 + j * 16 + mi;
            const int h = col >> 6, d = col & 63;
            #pragma unroll
            for (int i = 0; i < 4; ++i) {
                const int row = m0 + i * 16 + quad * 4;
                const int b = row >> 8;
                const int bh = b * 16 + h;
                #pragma unroll
                for (int r = 0; r < 4; ++r) {
                    int t = (row & 255) + r;
                    dst[(((size_t)bh * 256 + t) << 6) + d] =
                        f2bf(acc[i][j][r] + bT[(t < 2 ? t : 2) * 1024 + col]);
                }
            }
        }
    }
}

// ------------- pad V^T rows 64..79: row 64 = 1.0 (softmax-l trick), rows 65..79 = 0 -------------
__global__ __launch_bounds__(256) void vpad_kernel(u16* __restrict__ vt)
{
    const int bh = blockIdx.x;
    const int tid = threadIdx.x;
    const int rr = tid >> 4;            // 0..15 (row 64+rr)
    const int c0 = (tid & 15) * 16;     // 16 u16 per thread
    u32 fill = (rr == 0) ? 0x3F803F80u : 0u;
    uint4 val = make_uint4(fill, fill, fill, fill);
    uint4* p = (uint4*)(vt + (size_t)bh * 80 * 256 + (size_t)(64 + rr) * 256 + c0);
    p[0] = val;
    p[1] = val;
}

// ---------------- MFMA causal attention ----------------
// One block per (qt, bh): 1 wave (64 threads), 256 blocks total. Wave owns
// q-rows [64qt,64qt+64), loops key-tiles 0..qt. Max-free softmax; l via ones-row of V^T.
__global__ __launch_bounds__(64) void attn_mfma(
    const u16* __restrict__ qb, const u16* __restrict__ kb,
    const u16* __restrict__ vt, float* __restrict__ ao)
{
    __shared__ __align__(16) u16 P[64 * 72];    // stride 72 u16: 2-way banks only
    const int qt   = blockIdx.x;
    const int bh   = blockIdx.y;
    const int lane = threadIdx.x;
    const int mi   = lane & 15;
    const int quad = lane >> 4;

    const u16* Qb = qb + (((size_t)bh * 256 + qt * 64) << 6);
    const u16* Kb = kb + ((size_t)bh << 14);        // *256*64
    const u16* Vt = vt + (size_t)bh * 80 * 256;

    // Q fragments (persist across key tiles): A[m=mi][k=quad*8+j]
    bf16x8 qf[4][2];
    #pragma unroll
    for (int it = 0; it < 4; ++it)
        #pragma unroll
        for (int kc = 0; kc < 2; ++kc)
            qf[it][kc] = *(const bf16x8*)(Qb + ((it * 16 + mi) << 6) + kc * 32 + quad * 8);

    f32x4 o[4][5];
    #pragma unroll
    for (int it = 0; it < 4; ++it)
        #pragma unroll
        for (int jn = 0; jn < 5; ++jn)
            o[it][jn] = (f32x4){0.f, 0.f, 0.f, 0.f};

    for (int kt = 0; kt <= qt; ++kt) {
        // ---- S = Q @ K^T over this 64-key tile ----
        bf16x8 kf[4][2];
        #pragma unroll
        for (int jt = 0; jt < 4; ++jt)
            #pragma unroll
            for (int kc = 0; kc < 2; ++kc)
                kf[jt][kc] = *(const bf16x8*)(Kb + ((kt * 64 + jt * 16 + mi) << 6) + kc * 32 + quad * 8);

        f32x4 s[4][4];
        #pragma unroll
        for (int it = 0; it < 4; ++it)
            #pragma unroll
            for (int jt = 0; jt < 4; ++jt)
                s[it][jt] = (f32x4){0.f, 0.f, 0.f, 0.f};
        #pragma unroll
        for (int kc = 0; kc < 2; ++kc)
            #pragma unroll
            for (int it = 0; it < 4; ++it)
                #pragma unroll
                for (int jt = 0; jt < 4; ++jt)
                    s[it][jt] = __builtin_amdgcn_mfma_f32_16x16x32_bf16(qf[it][kc], kf[jt][kc], s[it][jt], 0, 0, 0);

        // ---- mask (diagonal tile only) + exp -> P (bf16, LDS, [row][key] stride 72) ----
        const bool diag = (kt == qt);
        #pragma unroll
        for (int it = 0; it < 4; ++it)
            #pragma unroll
            for (int jt = 0; jt < 4; ++jt)
                #pragma unroll
                for (int r = 0; r < 4; ++r) {
                    int qrow = it * 16 + quad * 4 + r;
                    int kcol = jt * 16 + mi;
                    float e = __expf(s[it][jt][r]);
                    if (diag && kcol > qrow) e = 0.f;
                    P[qrow * 72 + kcol] = f2bf(e);
                }

        // ---- PV: o += P @ [V | 1]^T  (A-frags from LDS, B-frags from V^T global) ----
        bf16x8 pf[4][2];
        #pragma unroll
        for (int it = 0; it < 4; ++it)
            #pragma unroll
            for (int kc = 0; kc < 2; ++kc)
                pf[it][kc] = *(const bf16x8*)(P + (it * 16 + mi) * 72 + kc * 32 + quad * 8);

        bf16x8 vf[5][2];
        #pragma unroll
        for (int jn = 0; jn < 5; ++jn)
            #pragma unroll
            for (int kc = 0; kc < 2; ++kc)
                vf[jn][kc] = *(const bf16x8*)(Vt + (size_t)(jn * 16 + mi) * 256 + kt * 64 + kc * 32 + quad * 8);

        #pragma unroll
        for (int kc = 0; kc < 2; ++kc)
            #pragma unroll
            for (int it = 0; it < 4; ++it)
                #pragma unroll
                for (int jn = 0; jn < 5; ++jn)
                    o[it][jn] = __builtin_amdgcn_mfma_f32_16x16x32_bf16(pf[it][kc], vf[jn][kc], o[it][jn], 0, 0, 0);
    }

    // ---- epilogue: l sits in n-tile 4 (ones row of V^T), lanes mi==0; broadcast & divide ----
    #pragma unroll
    for (int it = 0; it < 4; ++it) {
        float inv[4];
        #pragma unroll
        for (int r = 0; r < 4; ++r) {
            float lv = __shfl(o[it][4][r], (lane & 48));   // from lane quad*16+0
            inv[r] = 1.0f / lv;
        }
        #pragma unroll
        for (int jn = 0; jn < 4; ++jn)
            #pragma unroll
            for (int r = 0; r < 4; ++r) {
                int row = qt * 64 + it * 16 + quad * 4 + r;
                ao[(((size_t)bh * 256 + row) << 6) + jn * 16 + mi] = o[it][jn][r] * inv[r];
            }
    }
}

// ---------------- up-dense (64x64) + head-merge into [B, n, D] (bf16 out) ----------------
__global__ __launch_bounds__(256) void updense_kernel(
    const float* __restrict__ ao, const float* __restrict__ Wup,
    const float* __restrict__ bup, u16* __restrict__ ms)
{
    __shared__ float Ws[64 * 64];
    __shared__ float rows[4 * 64];
    const int tid = threadIdx.x;

    #pragma unroll
    for (int i = 0; i < 4; ++i)
        ((float4*)Ws)[tid + 256 * i] = ((const float4*)Wup)[tid + 256 * i];
    rows[tid] = ao[(size_t)blockIdx.x * 256 + tid];
    __syncthreads();

    const int r = tid >> 6, dp = tid & 63;
    const int R = blockIdx.x * 4 + r;
    const int b = R >> 12;
    const int h = (R >> 8) & 15;
    const int m = R & 255;

    float acc = bup[dp];
    #pragma unroll
    for (int d = 0; d < 64; ++d)
        acc += rows[r * 64 + d] * Ws[d * 64 + dp];

    ms[((size_t)(b * Nc + m) << 10) + h * 64 + dp] = f2bf(acc);
}

// ------------- final dense: C = ms @ Wtc^T + bc, fp32 [1024][1024] into ws -------------
// Same 1-wave 64x64 pipelined structure; grid 256 (16x16), K=1024 -> 16 steps.
__global__ __launch_bounds__(64) void gemm_out(
    const u16* __restrict__ A, const u16* __restrict__ Bt,
    const float* __restrict__ bias, float* __restrict__ C)
{
    __shared__ __align__(16) u16 S[2][2][4096];

    const int lane = threadIdx.x;
    const int mi   = lane & 15;
    const int quad = lane >> 4;

    const int bid = blockIdx.x;                   // 0..255
    const int wg  = (bid & 7) * 32 + (bid >> 3);  // bijective XCD chunking (256 = 8*32)
    const int m0  = (wg >> 4) * 64;
    const int n0  = (wg & 15) * 64;

    const char* Ab = (const char*)A  + (size_t)m0 * 2048;
    const char* Bb = (const char*)Bt + (size_t)n0 * 2048;

    f32x4 acc[4][4];
    #pragma unroll
    for (int i = 0; i < 4; ++i)
        #pragma unroll
        for (int j = 0; j < 4; ++j)
            acc[i][j] = (f32x4){0.f, 0.f, 0.f, 0.f};

    stage64(Ab, 0, S[0][0], lane, 2048);
    stage64(Bb, 0, S[0][1], lane, 2048);

    #pragma unroll 1
    for (int t = 0; t < 16; ++t) {
        const int cur = t & 1;
        if (t < 15) {
            stage64(Ab, (size_t)(t + 1) * 128, S[cur ^ 1][0], lane, 2048);
            stage64(Bb, (size_t)(t + 1) * 128, S[cur ^ 1][1], lane, 2048);
            asm volatile("s_waitcnt vmcnt(16)" ::: "memory");
        } else {
            asm volatile("s_waitcnt vmcnt(0)" ::: "memory");
        }
        __builtin_amdgcn_sched_barrier(0);

        bf16x8 af[4][2], bf[4][2];
        frag_read(S[cur][0], mi, quad, af);
        frag_read(S[cur][1], mi, quad, bf);

        #pragma unroll
        for (int kc = 0; kc < 2; ++kc)
            #pragma unroll
            for (int i = 0; i < 4; ++i)
                #pragma unroll
                for (int j = 0; j < 4; ++j)
                    acc[i][j] = __builtin_amdgcn_mfma_f32_16x16x32_bf16(af[i][kc], bf[j][kc], acc[i][j], 0, 0, 0);
    }

    #pragma unroll
    for (int j = 0; j < 4; ++j) {
        const int col = n0 + j * 16 + mi;
        const float bv = bias[col];
        #pragma unroll
        for (int i = 0; i < 4; ++i) {
            const int row = m0 + i * 16 + quad * 4;
            #pragma unroll
            for (int r = 0; r < 4; ++r)
                C[(size_t)(row + r) * 1024 + col] = acc[i][j][r] + bv;
        }
    }
}

// ------------- upsample 8x: out[b, t, :] = C[b*256 + t/8, :], coalesced float4 -------------
__global__ __launch_bounds__(256) void upsample_kernel(
    const float* __restrict__ C, float* __restrict__ out)
{
    const float4* C4  = (const float4*)C;
    float4*       out4 = (float4*)out;
    int idx0 = blockIdx.x * 1024 + threadIdx.x;
    #pragma unroll
    for (int rep = 0; rep < 4; ++rep) {
        int o4   = idx0 + rep * 256;       // over 2^21 float4s
        int col4 = o4 & 255;
        int rowo = o4 >> 8;                // 0..8191 output row
        int b    = rowo >> 11;
        int tc   = (rowo & 2047) >> 3;     // pooled row
        out4[o4] = C4[(size_t)((b << 8) + tc) * 256 + col4];
    }
}

extern "C" void kernel_launch(void* const* d_in, const int* in_sizes, int n_in,
                              void* d_out, int out_size, void* d_ws, size_t ws_size,
                              hipStream_t stream) {
    const float* q   = (const float*)d_in[0];
    const float* k   = (const float*)d_in[1];
    const float* v   = (const float*)d_in[2];
    const float* Wq  = (const float*)d_in[3];
    const float* bq  = (const float*)d_in[4];
    const float* Wk  = (const float*)d_in[5];
    const float* bk  = (const float*)d_in[6];
    const float* Wv  = (const float*)d_in[7];
    const float* bv  = (const float*)d_in[8];
    const float* Wup = (const float*)d_in[9];
    const float* bup = (const float*)d_in[10];
    const float* Wc  = (const float*)d_in[11];
    const float* bc  = (const float*)d_in[12];
    const float* wcq = (const float*)d_in[13];
    const float* bcq = (const float*)d_in[14];
    const float* wck = (const float*)d_in[15];
    const float* bck = (const float*)d_in[16];
    const float* wcv = (const float*)d_in[17];
    const float* bcv = (const float*)d_in[18];

    // A3 staging (18.9 MB bf16 [3][1024][3072]) lives in d_out; upsample rewrites
    // all of d_out at the end.
    u16* A3 = (u16*)d_out;

    char* wsb = (char*)d_ws;
    // ws layout (bytes), total 34.1 MB:
    //   0        : Wt3  bf16 [3][1024 n][3072 k]  18,874,368
    //   18874368 : Wtc  bf16 [1024][1024]          2,097,152
    //   20971520 : biasT f32 [3][3][1024]             36,864
    //   21008384 : qb   bf16 [64*256][64]          2,097,152
    //   23105536 : kb   bf16 [64*256][64]          2,097,152
    //   25202688 : vt   bf16 [64][80][256]         2,621,440
    //   27824128 : ao   fp32 [64*256][64]          4,194,304  (reused as C fp32)
    //   32018432 : ms   bf16 [1024][1024]          2,097,152
    u16*   Wt3   = (u16*)wsb;
    u16*   Wtc   = (u16*)(wsb + 18874368);
    float* biasT = (float*)(wsb + 20971520);
    u16*   qb    = (u16*)(wsb + 21008384);
    u16*   kb    = (u16*)(wsb + 23105536);
    u16*   vt    = (u16*)(wsb + 25202688);
    float* ao    = (float*)(wsb + 27824128);
    u16*   ms    = (u16*)(wsb + 32018432);
    float* Cf    = ao;   // ao is dead after updense_kernel; reuse for final-dense C

    // 1. weight prep: scaled+transposed Wt3 (q,k,v) + plain Wtc
    prep_wt3<<<dim3(16, 16, 4), 256, 0, stream>>>(Wq, Wk, Wv, Wc, wcq, wck, wcv, Wt3, Wtc);
    // 1b. bias table
    prep_bias<<<12, 256, 0, stream>>>(wcq, wck, wcv, bcq, bck, bcv, bq, bk, bv, biasT);
    // 2. stage differenced sections (K-concatenated) into d_out
    stage_kernel<<<3072, 256, 0, stream>>>(q, k, v, A3);
    // 3. fused QKV GEMM (1-wave 64x64 tiles, counted-vmcnt pipeline)
    gemm_qkv<<<768, 64, 0, stream>>>(A3, Wt3, biasT, qb, kb, vt);
    // 3b. V^T ones/zero pad rows (softmax-l trick)
    vpad_kernel<<<64, 256, 0, stream>>>(vt);
    // 4. MFMA causal attention, 256 one-wave blocks (all CUs)
    attn_mfma<<<dim3(4, 64), 64, 0, stream>>>(qb, kb, vt, ao);
    // 5. up-dense + merge heads -> ms bf16 [B*n][D]
    updense_kernel<<<(Bc * Hc * Nc) / 4, 256, 0, stream>>>(ao, Wup, bup, ms);
    // 6. final dense -> C fp32 (256 one-wave blocks)
    gemm_out<<<256, 64, 0, stream>>>(ms, Wtc, bc, Cf);
    // 7. 8x upsample broadcast, coalesced float4 writes
    upsample_kernel<<<2048, 256, 0, stream>>>(Cf, (float*)d_out);
}

// Round 6
// 250.527 us; speedup vs baseline: 1.1220x; 1.0260x over previous
//
#include <hip/hip_runtime.h>
#include <cstdint>
#include <cstddef>

// Problem constants
#define Bc  4
#define Sc  2048
#define Dc  1024
#define Hc  16
#define DDc 64
#define Nc  256   // pooled length

typedef unsigned short u16;
typedef unsigned int   u32;
typedef __bf16 bf16_t;
typedef bf16_t bf16x8 __attribute__((ext_vector_type(8)));
typedef float  f32x4  __attribute__((ext_vector_type(4)));

__device__ __forceinline__ u16 f2bf(float x) {
    u32 u = __float_as_uint(x);
    return (u16)((u + 0x7FFFu + ((u >> 16) & 1u)) >> 16);   // RNE
}
__device__ __forceinline__ u32 pack2(float a, float b) {
    return (u32)f2bf(a) | ((u32)f2bf(b) << 16);
}
__device__ __forceinline__ uint2 pack4(float4 x) {
    return make_uint2(pack2(x.x, x.y), pack2(x.z, x.w));
}
__device__ __forceinline__ float bf2f(u16 x) {
    return __uint_as_float((u32)x << 16);
}
__device__ __forceinline__ float4 f4add(float4 a, float4 b) {
    return make_float4(a.x + b.x, a.y + b.y, a.z + b.z, a.w + b.w);
}
__device__ __forceinline__ float4 f4sub(float4 a, float4 b) {
    return make_float4(a.x - b.x, a.y - b.y, a.z - b.z, a.w - b.w);
}

// async global->LDS, 16B per lane
__device__ __forceinline__ void gload_lds16(const void* gp, void* lp) {
    __builtin_amdgcn_global_load_lds(
        reinterpret_cast<const __attribute__((address_space(1))) void*>(
            reinterpret_cast<uintptr_t>(gp)),
        reinterpret_cast<__attribute__((address_space(3))) void*>(
            reinterpret_cast<uintptr_t>(lp)),
        16, 0, 0);
}

// ---- 1-wave GEMM building blocks (64x64 tile, BK=64, granule-swizzled LDS) ----
// Stage one 64-row x 128-byte K-slab into 8KB LDS. LDS slot (row r, granule g)
// receives global granule g ^ (r&7)  (8 granules of 16B per 128B row).
// Reader applies the same XOR -> bank-conflict-free, layout self-inverse.
__device__ __forceinline__ void stage64(const char* src, size_t kb, u16* lds,
                                        int lane, size_t rstride) {
    const int rowoff = lane >> 3;                       // 0..7
    const int srcg   = ((lane & 7) ^ (rowoff & 7)) * 16;
    const char* s0 = src + kb + (size_t)srcg;
    #pragma unroll
    for (int i = 0; i < 8; ++i)
        gload_lds16(s0 + (size_t)(8 * i + rowoff) * rstride,
                    (char*)lds + i * 1024);             // wave-uniform dest base
}

// Read 4x2 bf16x8 fragments (rows i*16+mi, K-halves kc) with the inverse XOR.
__device__ __forceinline__ void frag_read(const u16* lds, int mi, int quad,
                                          bf16x8 f[4][2]) {
    const int key = mi & 7;                             // (i*16+mi)&7 == mi&7
    #pragma unroll
    for (int i = 0; i < 4; ++i)
        #pragma unroll
        for (int kc = 0; kc < 2; ++kc) {
            int g = (kc * 4 + quad) ^ key;
            f[i][kc] = *(const bf16x8*)(lds + (i * 16 + mi) * 64 + g * 8);
        }
}

// ================= launch 1: prep_wt3 + prep_bias + stage, one dispatch =================
// blocks [0,1024)    : weight prep (z = bid>>8, k0 = ((bid>>4)&15)*64, n0 = (bid&15)*64)
// blocks [1024,1036) : bias table
// blocks [1036,4108) : input staging (XCD-chunk swizzled)
__global__ __launch_bounds__(256) void prep_stage(
    const float* __restrict__ q,  const float* __restrict__ k,  const float* __restrict__ v,
    const float* __restrict__ Wq, const float* __restrict__ Wk,
    const float* __restrict__ Wv, const float* __restrict__ Wc,
    const float* __restrict__ wcq, const float* __restrict__ wck, const float* __restrict__ wcv,
    const float* __restrict__ bcq, const float* __restrict__ bck, const float* __restrict__ bcv,
    const float* __restrict__ bq,  const float* __restrict__ bk,  const float* __restrict__ bv,
    u16* __restrict__ Wt3, u16* __restrict__ Wtc, float* __restrict__ biasT,
    u16* __restrict__ A3)
{
    __shared__ float T[64][65];
    const int bid = blockIdx.x;
    const int tid = threadIdx.x;

    if (bid < 1024) {
        // ---------------- weight prep ----------------
        const int z = bid >> 8;
        const float* W = (z == 0) ? Wq : (z == 1) ? Wk : (z == 2) ? Wv : Wc;
        const int k0 = ((bid >> 4) & 15) * 64, n0 = (bid & 15) * 64;
        const int c = tid & 63, r4 = tid >> 6;
        #pragma unroll
        for (int i = 0; i < 16; ++i) {
            int r = i * 4 + r4;
            T[r][c] = W[(size_t)(k0 + r) * 1024 + n0 + c];
        }
        __syncthreads();
        if (z < 3) {
            const float* wc = (z == 0) ? wcq : (z == 1) ? wck : wcv;
            const float fs = 0.125f * ((z == 2) ? 1.0f : 0.35355339059327373f);
            u16* dst0 = Wt3 + (size_t)z * 3145728;
            #pragma unroll
            for (int i = 0; i < 16; ++i) {
                int r = i * 4 + r4;
                int n = n0 + r;
                float w0 = wc[n], w1 = wc[1024 + n], w2 = wc[2048 + n];
                float s2 = fs * w2, s1 = s2 + fs * w1, s0 = s1 + fs * w0;
                float x = T[c][r];
                u16* dst = dst0 + (size_t)n * 3072 + k0 + c;
                dst[0]    = f2bf(x * s0);
                dst[1024] = f2bf(x * s1);
                dst[2048] = f2bf(x * s2);
            }
        } else {
            #pragma unroll
            for (int i = 0; i < 16; ++i) {
                int r = i * 4 + r4;
                Wtc[(size_t)(n0 + r) * 1024 + k0 + c] = f2bf(T[c][r]);
            }
        }
        return;
    }

    if (bid < 1036) {
        // ---------------- bias table: biasT[z][j][c], j = min(t,2) ----------------
        int gid = (bid - 1024) * 256 + tid;   // over 3*1024
        int c = gid & 1023, z = gid >> 10;
        const float* wc    = (z == 0) ? wcq : (z == 1) ? wck : wcv;
        const float* bconv = (z == 0) ? bcq : (z == 1) ? bck : bcv;
        const float* bl    = (z == 0) ? bq  : (z == 1) ? bk  : bv;
        const float nrm = (z == 2) ? 1.0f : 0.35355339059327373f;
        float w0 = wc[c], w1 = wc[1024 + c], w2 = wc[2048 + c];
        float bc_ = bconv[c], bl_ = bl[c];
        float* dst = biasT + (size_t)z * 3072 + c;
        dst[0]    = 0.125f * (bc_ + nrm * bl_ * w2);
        dst[1024] = 0.125f * (8.f * bc_ + nrm * bl_ * (7.f * w0 + 8.f * w1 + 8.f * w2));
        dst[2048] = 0.125f * (8.f * bc_ + nrm * bl_ * 8.f * (w0 + w1 + w2));
        return;
    }

    // ---------------- staging: differenced sections, K-concatenated ----------------
    // Thread t loads 10 contiguous rows [8t-9 .. 8t] (one float4 column slice):
    //   A0[t] = sum rows 8t-9..8t-2 ; B1[t] = x[8t-1]-x[8t-9] ; B2[t] = x[8t]-x[8t-8]
    // XCD-chunk swizzle so t and t+1 blocks share an XCD's L2 (boundary rows re-read).
    int sbid0 = bid - 1036;                             // 0..3071
    int sbid  = (sbid0 & 7) * 384 + (sbid0 >> 3);       // bijective (3072 = 8*384)
    int gid = sbid * 256 + tid;                         // over 3 * 2^18 float4-groups
    int c4 = gid & 255, t = (gid >> 8) & 255, b = (gid >> 16) & 3, inp = gid >> 18;
    const float* src = (inp == 0) ? q : (inp == 1) ? k : v;
    const float4* Xb = (const float4*)(src + (size_t)b * Sc * Dc) + c4;
    const float4* Xr = Xb + ((ptrdiff_t)(t << 3) - 9) * 256;   // row 8t-9

    float4 r[10];
    if (t >= 2) {
        #pragma unroll
        for (int i = 0; i < 10; ++i) r[i] = Xr[(ptrdiff_t)i * 256];
    } else if (t == 1) {
        r[0] = make_float4(0.f, 0.f, 0.f, 0.f);
        #pragma unroll
        for (int i = 1; i < 10; ++i) r[i] = Xr[(ptrdiff_t)i * 256];
    } else {
        #pragma unroll
        for (int i = 0; i < 9; ++i) r[i] = make_float4(0.f, 0.f, 0.f, 0.f);
        r[9] = Xr[(ptrdiff_t)9 * 256];
    }

    float4 A0 = f4add(f4add(f4add(r[0], r[1]), f4add(r[2], r[3])),
                      f4add(f4add(r[4], r[5]), f4add(r[6], r[7])));
    float4 B1 = f4sub(r[8], r[0]);
    float4 B2 = f4sub(r[9], r[1]);

    size_t s0 = (size_t)inp * 3145728 + (size_t)(b * 256 + t) * 3072 + c4 * 4;
    *(uint2*)(A3 + s0)        = pack4(A0);
    *(uint2*)(A3 + s0 + 1024) = pack4(B1);
    *(uint2*)(A3 + s0 + 2048) = pack4(B2);
}

// ====== launch 2: fused QKV GEMM + V^T pad, [1024 x 3072] @ Wt3_z^T + biasT ======
// blocks [0,768): 1-wave 64x64-tile GEMM (counted-vmcnt double-buffer, XCD swizzle)
// blocks [768,784): V^T pad rows 64..79 (row 64 = 1.0 softmax-l trick, rest 0)
__global__ __launch_bounds__(64) void gemm_qkv(
    const u16* __restrict__ A3, const u16* __restrict__ Wt3,
    const float* __restrict__ biasT,
    u16* __restrict__ qb, u16* __restrict__ kb, u16* __restrict__ vt)
{
    __shared__ __align__(16) u16 S[2][2][4096];   // [buf][A|B][64*64]

    const int lane = threadIdx.x;
    const int bid = blockIdx.x;

    if (bid >= 768) {
        // ---- vpad: 4 bh per block ----
        const int vb = bid - 768;                 // 0..15
        #pragma unroll
        for (int bh4 = 0; bh4 < 4; ++bh4) {
            const int bh = vb * 4 + bh4;
            #pragma unroll
            for (int it = 0; it < 8; ++it) {
                int gidx = it * 64 + lane;        // 512 uint4 per bh
                int row  = 64 + (gidx >> 5);
                int c0   = (gidx & 31) * 8;
                u32 fill = (row == 64) ? 0x3F803F80u : 0u;
                *(uint4*)(vt + (size_t)bh * 20480 + (size_t)row * 256 + c0) =
                    make_uint4(fill, fill, fill, fill);
            }
        }
        return;
    }

    const int mi   = lane & 15;
    const int quad = lane >> 4;

    const int wg  = (bid & 7) * 96 + (bid >> 3);  // bijective XCD chunking (768 = 8*96)
    const int z   = wg >> 8;
    const int m0  = ((wg >> 4) & 15) * 64;
    const int n0  = (wg & 15) * 64;

    const char* Ab = (const char*)(A3  + (size_t)z * 3145728) + (size_t)m0 * 6144;
    const char* Bb = (const char*)(Wt3 + (size_t)z * 3145728) + (size_t)n0 * 6144;

    f32x4 acc[4][4];
    #pragma unroll
    for (int i = 0; i < 4; ++i)
        #pragma unroll
        for (int j = 0; j < 4; ++j)
            acc[i][j] = (f32x4){0.f, 0.f, 0.f, 0.f};

    stage64(Ab, 0, S[0][0], lane, 6144);
    stage64(Bb, 0, S[0][1], lane, 6144);

    #pragma unroll 1
    for (int t = 0; t < 48; ++t) {
        const int cur = t & 1;
        if (t < 47) {
            stage64(Ab, (size_t)(t + 1) * 128, S[cur ^ 1][0], lane, 6144);
            stage64(Bb, (size_t)(t + 1) * 128, S[cur ^ 1][1], lane, 6144);
            asm volatile("s_waitcnt vmcnt(16)" ::: "memory");   // cur's 16 done, next 16 in flight
        } else {
            asm volatile("s_waitcnt vmcnt(0)" ::: "memory");
        }
        __builtin_amdgcn_sched_barrier(0);

        bf16x8 af[4][2], bf[4][2];
        frag_read(S[cur][0], mi, quad, af);
        frag_read(S[cur][1], mi, quad, bf);

        #pragma unroll
        for (int kc = 0; kc < 2; ++kc)
            #pragma unroll
            for (int i = 0; i < 4; ++i)
                #pragma unroll
                for (int j = 0; j < 4; ++j)
                    acc[i][j] = __builtin_amdgcn_mfma_f32_16x16x32_bf16(af[i][kc], bf[j][kc], acc[i][j], 0, 0, 0);
    }

    const float* bT = biasT + (size_t)z * 3072;
    if (z == 2) {
        #pragma unroll
        for (int j = 0; j < 4; ++j) {
            const int col = n0 + j * 16 + mi;
            const int h = col >> 6, d = col & 63;
            #pragma unroll
            for (int i = 0; i < 4; ++i) {
                const int row = m0 + i * 16 + quad * 4;
                const int b = row >> 8, t0 = row & 255;
                const int bh = b * 16 + h;
                u16 w[4];
                #pragma unroll
                for (int r = 0; r < 4; ++r) {
                    int t = t0 + r;
                    w[r] = f2bf(acc[i][j][r] + bT[(t < 2 ? t : 2) * 1024 + col]);
                }
                *(uint2*)(vt + (size_t)bh * 20480 + (size_t)d * 256 + t0) =
                    make_uint2((u32)w[0] | ((u32)w[1] << 16), (u32)w[2] | ((u32)w[3] << 16));
            }
        }
    } else {
        u16* dst = z ? kb : qb;
        #pragma unroll
        for (int j = 0; j < 4; ++j) {
            const int col = n0 + j * 16 + mi;
            const int h = col >> 6, d = col & 63;
            #pragma unroll
            for (int i = 0; i < 4; ++i) {
                const int row = m0 + i * 16 + quad * 4;
                const int b = row >> 8;
                const int bh = b * 16 + h;
                #pragma unroll
                for (int r = 0; r < 4; ++r) {
                    int t = (row & 255) + r;
                    dst[(((size_t)bh * 256 + t) << 6) + d] =
                        f2bf(acc[i][j][r] + bT[(t < 2 ? t : 2) * 1024 + col]);
                }
            }
        }
    }
}

// ---------------- launch 3: MFMA causal attention ----------------
// One block per (qt, bh): 1 wave (64 threads), 256 blocks total. Wave owns
// q-rows [64qt,64qt+64), loops key-tiles 0..qt. Max-free softmax; l via ones-row of V^T.
__global__ __launch_bounds__(64) void attn_mfma(
    const u16* __restrict__ qb, const u16* __restrict__ kb,
    const u16* __restrict__ vt, float* __restrict__ ao)
{
    __shared__ __align__(16) u16 P[64 * 72];    // stride 72 u16: 2-way banks only
    const int qt   = blockIdx.x;
    const int bh   = blockIdx.y;
    const int lane = threadIdx.x;
    const int mi   = lane & 15;
    const int quad = lane >> 4;

    const u16* Qb = qb + (((size_t)bh * 256 + qt * 64) << 6);
    const u16* Kb = kb + ((size_t)bh << 14);        // *256*64
    const u16* Vt = vt + (size_t)bh * 80 * 256;

    // Q fragments (persist across key tiles): A[m=mi][k=quad*8+j]
    bf16x8 qf[4][2];
    #pragma unroll
    for (int it = 0; it < 4; ++it)
        #pragma unroll
        for (int kc = 0; kc < 2; ++kc)
            qf[it][kc] = *(const bf16x8*)(Qb + ((it * 16 + mi) << 6) + kc * 32 + quad * 8);

    f32x4 o[4][5];
    #pragma unroll
    for (int it = 0; it < 4; ++it)
        #pragma unroll
        for (int jn = 0; jn < 5; ++jn)
            o[it][jn] = (f32x4){0.f, 0.f, 0.f, 0.f};

    for (int kt = 0; kt <= qt; ++kt) {
        // ---- S = Q @ K^T over this 64-key tile ----
        bf16x8 kf[4][2];
        #pragma unroll
        for (int jt = 0; jt < 4; ++jt)
            #pragma unroll
            for (int kc = 0; kc < 2; ++kc)
                kf[jt][kc] = *(const bf16x8*)(Kb + ((kt * 64 + jt * 16 + mi) << 6) + kc * 32 + quad * 8);

        f32x4 s[4][4];
        #pragma unroll
        for (int it = 0; it < 4; ++it)
            #pragma unroll
            for (int jt = 0; jt < 4; ++jt)
                s[it][jt] = (f32x4){0.f, 0.f, 0.f, 0.f};
        #pragma unroll
        for (int kc = 0; kc < 2; ++kc)
            #pragma unroll
            for (int it = 0; it < 4; ++it)
                #pragma unroll
                for (int jt = 0; jt < 4; ++jt)
                    s[it][jt] = __builtin_amdgcn_mfma_f32_16x16x32_bf16(qf[it][kc], kf[jt][kc], s[it][jt], 0, 0, 0);

        // ---- mask (diagonal tile only) + exp -> P (bf16, LDS, [row][key] stride 72) ----
        const bool diag = (kt == qt);
        #pragma unroll
        for (int it = 0; it < 4; ++it)
            #pragma unroll
            for (int jt = 0; jt < 4; ++jt)
                #pragma unroll
                for (int r = 0; r < 4; ++r) {
                    int qrow = it * 16 + quad * 4 + r;
                    int kcol = jt * 16 + mi;
                    float e = __expf(s[it][jt][r]);
                    if (diag && kcol > qrow) e = 0.f;
                    P[qrow * 72 + kcol] = f2bf(e);
                }

        // ---- PV: o += P @ [V | 1]^T  (A-frags from LDS, B-frags from V^T global) ----
        bf16x8 pf[4][2];
        #pragma unroll
        for (int it = 0; it < 4; ++it)
            #pragma unroll
            for (int kc = 0; kc < 2; ++kc)
                pf[it][kc] = *(const bf16x8*)(P + (it * 16 + mi) * 72 + kc * 32 + quad * 8);

        bf16x8 vf[5][2];
        #pragma unroll
        for (int jn = 0; jn < 5; ++jn)
            #pragma unroll
            for (int kc = 0; kc < 2; ++kc)
                vf[jn][kc] = *(const bf16x8*)(Vt + (size_t)(jn * 16 + mi) * 256 + kt * 64 + kc * 32 + quad * 8);

        #pragma unroll
        for (int kc = 0; kc < 2; ++kc)
            #pragma unroll
            for (int it = 0; it < 4; ++it)
                #pragma unroll
                for (int jn = 0; jn < 5; ++jn)
                    o[it][jn] = __builtin_amdgcn_mfma_f32_16x16x32_bf16(pf[it][kc], vf[jn][kc], o[it][jn], 0, 0, 0);
    }

    // ---- epilogue: l sits in n-tile 4 (ones row of V^T), lanes mi==0; broadcast & divide ----
    #pragma unroll
    for (int it = 0; it < 4; ++it) {
        float inv[4];
        #pragma unroll
        for (int r = 0; r < 4; ++r) {
            float lv = __shfl(o[it][4][r], (lane & 48));   // from lane quad*16+0
            inv[r] = 1.0f / lv;
        }
        #pragma unroll
        for (int jn = 0; jn < 4; ++jn)
            #pragma unroll
            for (int r = 0; r < 4; ++r) {
                int row = qt * 64 + it * 16 + quad * 4 + r;
                ao[(((size_t)bh * 256 + row) << 6) + jn * 16 + mi] = o[it][jn][r] * inv[r];
            }
    }
}

// -------- launch 4: up-dense (64x64) + head-merge into [B, n, D] (bf16 out) --------
__global__ __launch_bounds__(256) void updense_kernel(
    const float* __restrict__ ao, const float* __restrict__ Wup,
    const float* __restrict__ bup, u16* __restrict__ ms)
{
    __shared__ float Ws[64 * 64];
    __shared__ float rows[4 * 64];
    const int tid = threadIdx.x;

    #pragma unroll
    for (int i = 0; i < 4; ++i)
        ((float4*)Ws)[tid + 256 * i] = ((const float4*)Wup)[tid + 256 * i];
    rows[tid] = ao[(size_t)blockIdx.x * 256 + tid];
    __syncthreads();

    const int r = tid >> 6, dp = tid & 63;
    const int R = blockIdx.x * 4 + r;
    const int b = R >> 12;
    const int h = (R >> 8) & 15;
    const int m = R & 255;

    float acc = bup[dp];
    #pragma unroll
    for (int d = 0; d < 64; ++d)
        acc += rows[r * 64 + d] * Ws[d * 64 + dp];

    ms[((size_t)(b * Nc + m) << 10) + h * 64 + dp] = f2bf(acc);
}

// ====== launch 5: final dense + fused 8x upsample, straight into d_out ======
// 1-wave 64x64 pipelined GEMM (K=1024, 16 steps); C-tile staged to padded LDS,
// then 8x-replicated coalesced float4 stores (no intermediate C buffer).
__global__ __launch_bounds__(64) void gemm_out_up(
    const u16* __restrict__ A, const u16* __restrict__ Bt,
    const float* __restrict__ bias, float* __restrict__ out)
{
    __shared__ __align__(16) u16 S[2][2][4096];
    __shared__ __align__(16) float Cs[64][68];    // pad 68: 16B-aligned rows

    const int lane = threadIdx.x;
    const int mi   = lane & 15;
    const int quad = lane >> 4;

    const int bid = blockIdx.x;                   // 0..255
    const int wg  = (bid & 7) * 32 + (bid >> 3);  // bijective XCD chunking (256 = 8*32)
    const int m0  = (wg >> 4) * 64;
    const int n0  = (wg & 15) * 64;

    const char* Ab = (const char*)A  + (size_t)m0 * 2048;
    const char* Bb = (const char*)Bt + (size_t)n0 * 2048;

    f32x4 acc[4][4];
    #pragma unroll
    for (int i = 0; i < 4; ++i)
        #pragma unroll
        for (int j = 0; j < 4; ++j)
            acc[i][j] = (f32x4){0.f, 0.f, 0.f, 0.f};

    stage64(Ab, 0, S[0][0], lane, 2048);
    stage64(Bb, 0, S[0][1], lane, 2048);

    #pragma unroll 1
    for (int t = 0; t < 16; ++t) {
        const int cur = t & 1;
        if (t < 15) {
            stage64(Ab, (size_t)(t + 1) * 128, S[cur ^ 1][0], lane, 2048);
            stage64(Bb, (size_t)(t + 1) * 128, S[cur ^ 1][1], lane, 2048);
            asm volatile("s_waitcnt vmcnt(16)" ::: "memory");
        } else {
            asm volatile("s_waitcnt vmcnt(0)" ::: "memory");
        }
        __builtin_amdgcn_sched_barrier(0);

        bf16x8 af[4][2], bf[4][2];
        frag_read(S[cur][0], mi, quad, af);
        frag_read(S[cur][1], mi, quad, bf);

        #pragma unroll
        for (int kc = 0; kc < 2; ++kc)
            #pragma unroll
            for (int i = 0; i < 4; ++i)
                #pragma unroll
                for (int j = 0; j < 4; ++j)
                    acc[i][j] = __builtin_amdgcn_mfma_f32_16x16x32_bf16(af[i][kc], bf[j][kc], acc[i][j], 0, 0, 0);
    }

    // C-tile (+bias) to LDS
    #pragma unroll
    for (int j = 0; j < 4; ++j) {
        const float bv = bias[n0 + j * 16 + mi];
        #pragma unroll
        for (int i = 0; i < 4; ++i)
            #pragma unroll
            for (int r = 0; r < 4; ++r)
                Cs[i * 16 + quad * 4 + r][j * 16 + mi] = acc[i][j][r] + bv;
    }

    // 8x broadcast write-out: 64 C-rows x 8 reps x 64 cols = 8192 float4
    // per iter: all lanes share one C-row (broadcast LDS read), 4 reps x 16 col4.
    const int col4 = lane & 15;
    #pragma unroll 4
    for (int it = 0; it < 128; ++it) {
        const int crow = it >> 1;
        const int rep  = ((it & 1) << 2) + (lane >> 4);
        float4 val = *(const float4*)&Cs[crow][col4 * 4];
        const int R = m0 + crow;
        const int b = R >> 8, tc = R & 255;
        float* po = out + (((size_t)((b << 11) + (tc << 3) + rep)) << 10) + n0 + (col4 << 2);
        *(float4*)po = val;
    }
}

extern "C" void kernel_launch(void* const* d_in, const int* in_sizes, int n_in,
                              void* d_out, int out_size, void* d_ws, size_t ws_size,
                              hipStream_t stream) {
    const float* q   = (const float*)d_in[0];
    const float* k   = (const float*)d_in[1];
    const float* v   = (const float*)d_in[2];
    const float* Wq  = (const float*)d_in[3];
    const float* bq  = (const float*)d_in[4];
    const float* Wk  = (const float*)d_in[5];
    const float* bk  = (const float*)d_in[6];
    const float* Wv  = (const float*)d_in[7];
    const float* bv  = (const float*)d_in[8];
    const float* Wup = (const float*)d_in[9];
    const float* bup = (const float*)d_in[10];
    const float* Wc  = (const float*)d_in[11];
    const float* bc  = (const float*)d_in[12];
    const float* wcq = (const float*)d_in[13];
    const float* bcq = (const float*)d_in[14];
    const float* wck = (const float*)d_in[15];
    const float* bck = (const float*)d_in[16];
    const float* wcv = (const float*)d_in[17];
    const float* bcv = (const float*)d_in[18];

    // A3 staging (18.9 MB bf16 [3][1024][3072]) lives in d_out; gemm_out_up
    // rewrites all of d_out at the end.
    u16* A3 = (u16*)d_out;

    char* wsb = (char*)d_ws;
    // ws layout (bytes), total 34.1 MB:
    //   0        : Wt3  bf16 [3][1024 n][3072 k]  18,874,368
    //   18874368 : Wtc  bf16 [1024][1024]          2,097,152
    //   20971520 : biasT f32 [3][3][1024]             36,864
    //   21008384 : qb   bf16 [64*256][64]          2,097,152
    //   23105536 : kb   bf16 [64*256][64]          2,097,152
    //   25202688 : vt   bf16 [64][80][256]         2,621,440
    //   27824128 : ao   fp32 [64*256][64]          4,194,304
    //   32018432 : ms   bf16 [1024][1024]          2,097,152
    u16*   Wt3   = (u16*)wsb;
    u16*   Wtc   = (u16*)(wsb + 18874368);
    float* biasT = (float*)(wsb + 20971520);
    u16*   qb    = (u16*)(wsb + 21008384);
    u16*   kb    = (u16*)(wsb + 23105536);
    u16*   vt    = (u16*)(wsb + 25202688);
    float* ao    = (float*)(wsb + 27824128);
    u16*   ms    = (u16*)(wsb + 32018432);

    // 1. weight prep + bias table + input staging (one dispatch)
    prep_stage<<<4108, 256, 0, stream>>>(q, k, v, Wq, Wk, Wv, Wc,
                                         wcq, wck, wcv, bcq, bck, bcv,
                                         bq, bk, bv, Wt3, Wtc, biasT, A3);
    // 2. fused QKV GEMM + V^T pad (784 one-wave blocks)
    gemm_qkv<<<784, 64, 0, stream>>>(A3, Wt3, biasT, qb, kb, vt);
    // 3. MFMA causal attention, 256 one-wave blocks (all CUs)
    attn_mfma<<<dim3(4, 64), 64, 0, stream>>>(qb, kb, vt, ao);
    // 4. up-dense + merge heads -> ms bf16 [B*n][D]
    updense_kernel<<<(Bc * Hc * Nc) / 4, 256, 0, stream>>>(ao, Wup, bup, ms);
    // 5. final dense + fused 8x upsample -> d_out (256 one-wave blocks)
    gemm_out_up<<<256, 64, 0, stream>>>(ms, Wtc, bc, (float*)d_out);
}

// Round 7
// 243.631 us; speedup vs baseline: 1.1538x; 1.0283x over previous
//
#include <hip/hip_runtime.h>
#include <cstdint>
#include <cstddef>

// Problem constants
#define Bc  4
#define Sc  2048
#define Dc  1024
#define Hc  16
#define DDc 64
#define Nc  256   // pooled length

typedef unsigned short u16;
typedef unsigned int   u32;
typedef __bf16 bf16_t;
typedef bf16_t bf16x8 __attribute__((ext_vector_type(8)));
typedef float  f32x4  __attribute__((ext_vector_type(4)));

__device__ __forceinline__ u16 f2bf(float x) {
    u32 u = __float_as_uint(x);
    return (u16)((u + 0x7FFFu + ((u >> 16) & 1u)) >> 16);   // RNE
}
__device__ __forceinline__ u32 pack2(float a, float b) {
    return (u32)f2bf(a) | ((u32)f2bf(b) << 16);
}
__device__ __forceinline__ uint2 pack4(float4 x) {
    return make_uint2(pack2(x.x, x.y), pack2(x.z, x.w));
}
__device__ __forceinline__ float bf2f(u16 x) {
    return __uint_as_float((u32)x << 16);
}
__device__ __forceinline__ float4 f4add(float4 a, float4 b) {
    return make_float4(a.x + b.x, a.y + b.y, a.z + b.z, a.w + b.w);
}
__device__ __forceinline__ float4 f4sub(float4 a, float4 b) {
    return make_float4(a.x - b.x, a.y - b.y, a.z - b.z, a.w - b.w);
}

// async global->LDS, 16B per lane
__device__ __forceinline__ void gload_lds16(const void* gp, void* lp) {
    __builtin_amdgcn_global_load_lds(
        reinterpret_cast<const __attribute__((address_space(1))) void*>(
            reinterpret_cast<uintptr_t>(gp)),
        reinterpret_cast<__attribute__((address_space(3))) void*>(
            reinterpret_cast<uintptr_t>(lp)),
        16, 0, 0);
}

// ---- 1-wave GEMM building blocks (64x64 tile, BK=64, granule-swizzled LDS) ----
// Stage one 64-row x 128-byte K-slab into 8KB LDS. LDS slot (row r, granule g)
// receives global granule g ^ (r&7)  (8 granules of 16B per 128B row).
// Reader applies the same XOR -> bank-conflict-free, layout self-inverse.
__device__ __forceinline__ void stage64(const char* src, size_t kb, u16* lds,
                                        int lane, size_t rstride) {
    const int rowoff = lane >> 3;                       // 0..7
    const int srcg   = ((lane & 7) ^ (rowoff & 7)) * 16;
    const char* s0 = src + kb + (size_t)srcg;
    #pragma unroll
    for (int i = 0; i < 8; ++i)
        gload_lds16(s0 + (size_t)(8 * i + rowoff) * rstride,
                    (char*)lds + i * 1024);             // wave-uniform dest base
}

// Read 4x2 bf16x8 fragments (rows i*16+mi, K-halves kc) with the inverse XOR.
__device__ __forceinline__ void frag_read(const u16* lds, int mi, int quad,
                                          bf16x8 f[4][2]) {
    const int key = mi & 7;                             // (i*16+mi)&7 == mi&7
    #pragma unroll
    for (int i = 0; i < 4; ++i)
        #pragma unroll
        for (int kc = 0; kc < 2; ++kc) {
            int g = (kc * 4 + quad) ^ key;
            f[i][kc] = *(const bf16x8*)(lds + (i * 16 + mi) * 64 + g * 8);
        }
}

// ================= launch 1: prep + bias + WupT + stage, one dispatch =================
// blocks [0,1024)    : weight prep (z = bid>>8, k0 = ((bid>>4)&15)*64, n0 = (bid&15)*64)
// blocks [1024,1036) : bias table
// block  1036        : Wup transpose -> WupT bf16 [dp][d]
// blocks [1037,4109) : input staging (XCD-chunk swizzled)
__global__ __launch_bounds__(256) void prep_stage(
    const float* __restrict__ q,  const float* __restrict__ k,  const float* __restrict__ v,
    const float* __restrict__ Wq, const float* __restrict__ Wk,
    const float* __restrict__ Wv, const float* __restrict__ Wc,
    const float* __restrict__ Wup,
    const float* __restrict__ wcq, const float* __restrict__ wck, const float* __restrict__ wcv,
    const float* __restrict__ bcq, const float* __restrict__ bck, const float* __restrict__ bcv,
    const float* __restrict__ bq,  const float* __restrict__ bk,  const float* __restrict__ bv,
    u16* __restrict__ Wt3, u16* __restrict__ Wtc, float* __restrict__ biasT,
    u16* __restrict__ WupT, u16* __restrict__ A3)
{
    __shared__ float T[64][65];
    const int bid = blockIdx.x;
    const int tid = threadIdx.x;

    if (bid < 1024) {
        // ---------------- weight prep ----------------
        const int z = bid >> 8;
        const float* W = (z == 0) ? Wq : (z == 1) ? Wk : (z == 2) ? Wv : Wc;
        const int k0 = ((bid >> 4) & 15) * 64, n0 = (bid & 15) * 64;
        const int c = tid & 63, r4 = tid >> 6;
        #pragma unroll
        for (int i = 0; i < 16; ++i) {
            int r = i * 4 + r4;
            T[r][c] = W[(size_t)(k0 + r) * 1024 + n0 + c];
        }
        __syncthreads();
        if (z < 3) {
            const float* wc = (z == 0) ? wcq : (z == 1) ? wck : wcv;
            const float fs = 0.125f * ((z == 2) ? 1.0f : 0.35355339059327373f);
            u16* dst0 = Wt3 + (size_t)z * 3145728;
            #pragma unroll
            for (int i = 0; i < 16; ++i) {
                int r = i * 4 + r4;
                int n = n0 + r;
                float w0 = wc[n], w1 = wc[1024 + n], w2 = wc[2048 + n];
                float s2 = fs * w2, s1 = s2 + fs * w1, s0 = s1 + fs * w0;
                float x = T[c][r];
                u16* dst = dst0 + (size_t)n * 3072 + k0 + c;
                dst[0]    = f2bf(x * s0);
                dst[1024] = f2bf(x * s1);
                dst[2048] = f2bf(x * s2);
            }
        } else {
            #pragma unroll
            for (int i = 0; i < 16; ++i) {
                int r = i * 4 + r4;
                Wtc[(size_t)(n0 + r) * 1024 + k0 + c] = f2bf(T[c][r]);
            }
        }
        return;
    }

    if (bid < 1036) {
        // ---------------- bias table: biasT[z][j][c], j = min(t,2) ----------------
        int gid = (bid - 1024) * 256 + tid;   // over 3*1024
        int c = gid & 1023, z = gid >> 10;
        const float* wc    = (z == 0) ? wcq : (z == 1) ? wck : wcv;
        const float* bconv = (z == 0) ? bcq : (z == 1) ? bck : bcv;
        const float* bl    = (z == 0) ? bq  : (z == 1) ? bk  : bv;
        const float nrm = (z == 2) ? 1.0f : 0.35355339059327373f;
        float w0 = wc[c], w1 = wc[1024 + c], w2 = wc[2048 + c];
        float bc_ = bconv[c], bl_ = bl[c];
        float* dst = biasT + (size_t)z * 3072 + c;
        dst[0]    = 0.125f * (bc_ + nrm * bl_ * w2);
        dst[1024] = 0.125f * (8.f * bc_ + nrm * bl_ * (7.f * w0 + 8.f * w1 + 8.f * w2));
        dst[2048] = 0.125f * (8.f * bc_ + nrm * bl_ * 8.f * (w0 + w1 + w2));
        return;
    }

    if (bid == 1036) {
        // ---------------- Wup transpose: WupT[dp][d] = Wup[d][dp], bf16 ----------------
        const int c = tid & 63, r4 = tid >> 6;
        #pragma unroll
        for (int i = 0; i < 16; ++i) {
            int r = i * 4 + r4;
            T[r][c] = Wup[r * 64 + c];
        }
        __syncthreads();
        #pragma unroll
        for (int i = 0; i < 16; ++i) {
            int r = i * 4 + r4;
            WupT[r * 64 + c] = f2bf(T[c][r]);
        }
        return;
    }

    // ---------------- staging: differenced sections, K-concatenated ----------------
    // Thread t loads 10 contiguous rows [8t-9 .. 8t] (one float4 column slice):
    //   A0[t] = sum rows 8t-9..8t-2 ; B1[t] = x[8t-1]-x[8t-9] ; B2[t] = x[8t]-x[8t-8]
    // sched_barrier between loads and math: forces all 10 loads issued before any
    // consumer -> 40+ VGPRs live (r6 showed VGPR=32 => serialized loads, 2.2 TB/s).
    int sbid0 = bid - 1037;                             // 0..3071
    int sbid  = (sbid0 & 7) * 384 + (sbid0 >> 3);       // bijective (3072 = 8*384)
    int gid = sbid * 256 + tid;                         // over 3 * 2^18 float4-groups
    int c4 = gid & 255, t = (gid >> 8) & 255, b = (gid >> 16) & 3, inp = gid >> 18;
    const float* src = (inp == 0) ? q : (inp == 1) ? k : v;
    const float4* Xb = (const float4*)(src + (size_t)b * Sc * Dc) + c4;
    const float4* Xr = Xb + ((ptrdiff_t)(t << 3) - 9) * 256;   // row 8t-9

    float4 r[10];
    if (t >= 2) {
        #pragma unroll
        for (int i = 0; i < 10; ++i) r[i] = Xr[(ptrdiff_t)i * 256];
    } else if (t == 1) {
        r[0] = make_float4(0.f, 0.f, 0.f, 0.f);
        #pragma unroll
        for (int i = 1; i < 10; ++i) r[i] = Xr[(ptrdiff_t)i * 256];
    } else {
        #pragma unroll
        for (int i = 0; i < 9; ++i) r[i] = make_float4(0.f, 0.f, 0.f, 0.f);
        r[9] = Xr[(ptrdiff_t)9 * 256];
    }
    __builtin_amdgcn_sched_barrier(0);   // all loads issued before any add

    float4 A0 = f4add(f4add(f4add(r[0], r[1]), f4add(r[2], r[3])),
                      f4add(f4add(r[4], r[5]), f4add(r[6], r[7])));
    float4 B1 = f4sub(r[8], r[0]);
    float4 B2 = f4sub(r[9], r[1]);

    size_t s0 = (size_t)inp * 3145728 + (size_t)(b * 256 + t) * 3072 + c4 * 4;
    *(uint2*)(A3 + s0)        = pack4(A0);
    *(uint2*)(A3 + s0 + 1024) = pack4(B1);
    *(uint2*)(A3 + s0 + 2048) = pack4(B2);
}

// ====== launch 2: fused QKV GEMM + V^T pad, [1024 x 3072] @ Wt3_z^T + biasT ======
// blocks [0,768): 1-wave 64x64-tile GEMM (counted-vmcnt double-buffer, XCD swizzle)
// blocks [768,784): V^T pad rows 64..79 (row 64 = 1.0 softmax-l trick, rest 0)
__global__ __launch_bounds__(64) void gemm_qkv(
    const u16* __restrict__ A3, const u16* __restrict__ Wt3,
    const float* __restrict__ biasT,
    u16* __restrict__ qb, u16* __restrict__ kb, u16* __restrict__ vt)
{
    __shared__ __align__(16) u16 S[2][2][4096];   // [buf][A|B][64*64]

    const int lane = threadIdx.x;
    const int bid = blockIdx.x;

    if (bid >= 768) {
        // ---- vpad: 4 bh per block ----
        const int vb = bid - 768;                 // 0..15
        #pragma unroll
        for (int bh4 = 0; bh4 < 4; ++bh4) {
            const int bh = vb * 4 + bh4;
            #pragma unroll
            for (int it = 0; it < 8; ++it) {
                int gidx = it * 64 + lane;        // 512 uint4 per bh
                int row  = 64 + (gidx >> 5);
                int c0   = (gidx & 31) * 8;
                u32 fill = (row == 64) ? 0x3F803F80u : 0u;
                *(uint4*)(vt + (size_t)bh * 20480 + (size_t)row * 256 + c0) =
                    make_uint4(fill, fill, fill, fill);
            }
        }
        return;
    }

    const int mi   = lane & 15;
    const int quad = lane >> 4;

    const int wg  = (bid & 7) * 96 + (bid >> 3);  // bijective XCD chunking (768 = 8*96)
    const int z   = wg >> 8;
    const int m0  = ((wg >> 4) & 15) * 64;
    const int n0  = (wg & 15) * 64;

    const char* Ab = (const char*)(A3  + (size_t)z * 3145728) + (size_t)m0 * 6144;
    const char* Bb = (const char*)(Wt3 + (size_t)z * 3145728) + (size_t)n0 * 6144;

    f32x4 acc[4][4];
    #pragma unroll
    for (int i = 0; i < 4; ++i)
        #pragma unroll
        for (int j = 0; j < 4; ++j)
            acc[i][j] = (f32x4){0.f, 0.f, 0.f, 0.f};

    stage64(Ab, 0, S[0][0], lane, 6144);
    stage64(Bb, 0, S[0][1], lane, 6144);

    #pragma unroll 1
    for (int t = 0; t < 48; ++t) {
        const int cur = t & 1;
        if (t < 47) {
            stage64(Ab, (size_t)(t + 1) * 128, S[cur ^ 1][0], lane, 6144);
            stage64(Bb, (size_t)(t + 1) * 128, S[cur ^ 1][1], lane, 6144);
            asm volatile("s_waitcnt vmcnt(16)" ::: "memory");   // cur's 16 done, next 16 in flight
        } else {
            asm volatile("s_waitcnt vmcnt(0)" ::: "memory");
        }
        __builtin_amdgcn_sched_barrier(0);

        bf16x8 af[4][2], bf[4][2];
        frag_read(S[cur][0], mi, quad, af);
        frag_read(S[cur][1], mi, quad, bf);

        #pragma unroll
        for (int kc = 0; kc < 2; ++kc)
            #pragma unroll
            for (int i = 0; i < 4; ++i)
                #pragma unroll
                for (int j = 0; j < 4; ++j)
                    acc[i][j] = __builtin_amdgcn_mfma_f32_16x16x32_bf16(af[i][kc], bf[j][kc], acc[i][j], 0, 0, 0);
    }

    const float* bT = biasT + (size_t)z * 3072;
    if (z == 2) {
        #pragma unroll
        for (int j = 0; j < 4; ++j) {
            const int col = n0 + j * 16 + mi;
            const int h = col >> 6, d = col & 63;
            #pragma unroll
            for (int i = 0; i < 4; ++i) {
                const int row = m0 + i * 16 + quad * 4;
                const int b = row >> 8, t0 = row & 255;
                const int bh = b * 16 + h;
                u16 w[4];
                #pragma unroll
                for (int r = 0; r < 4; ++r) {
                    int t = t0 + r;
                    w[r] = f2bf(acc[i][j][r] + bT[(t < 2 ? t : 2) * 1024 + col]);
                }
                *(uint2*)(vt + (size_t)bh * 20480 + (size_t)d * 256 + t0) =
                    make_uint2((u32)w[0] | ((u32)w[1] << 16), (u32)w[2] | ((u32)w[3] << 16));
            }
        }
    } else {
        u16* dst = z ? kb : qb;
        #pragma unroll
        for (int j = 0; j < 4; ++j) {
            const int col = n0 + j * 16 + mi;
            const int h = col >> 6, d = col & 63;
            #pragma unroll
            for (int i = 0; i < 4; ++i) {
                const int row = m0 + i * 16 + quad * 4;
                const int b = row >> 8;
                const int bh = b * 16 + h;
                #pragma unroll
                for (int r = 0; r < 4; ++r) {
                    int t = (row & 255) + r;
                    dst[(((size_t)bh * 256 + t) << 6) + d] =
                        f2bf(acc[i][j][r] + bT[(t < 2 ? t : 2) * 1024 + col]);
                }
            }
        }
    }
}

// ---------------- launch 3: MFMA causal attention + fused up-dense ----------------
// One block per (qt, bh): 1 wave. After online attention, normalize -> G bf16 in P
// LDS -> MFMA against WupT + bup -> ms directly (updense kernel deleted).
__global__ __launch_bounds__(64) void attn_mfma(
    const u16* __restrict__ qb, const u16* __restrict__ kb,
    const u16* __restrict__ vt, const u16* __restrict__ WupT,
    const float* __restrict__ bup, u16* __restrict__ ms)
{
    __shared__ __align__(16) u16 P[64 * 72];    // stride 72 u16: 2-way banks only
    const int qt   = blockIdx.x;
    const int bh   = blockIdx.y;
    const int lane = threadIdx.x;
    const int mi   = lane & 15;
    const int quad = lane >> 4;

    const u16* Qb = qb + (((size_t)bh * 256 + qt * 64) << 6);
    const u16* Kb = kb + ((size_t)bh << 14);        // *256*64
    const u16* Vt = vt + (size_t)bh * 80 * 256;

    // Q fragments (persist across key tiles): A[m=mi][k=quad*8+j]
    bf16x8 qf[4][2];
    #pragma unroll
    for (int it = 0; it < 4; ++it)
        #pragma unroll
        for (int kc = 0; kc < 2; ++kc)
            qf[it][kc] = *(const bf16x8*)(Qb + ((it * 16 + mi) << 6) + kc * 32 + quad * 8);

    f32x4 o[4][5];
    #pragma unroll
    for (int it = 0; it < 4; ++it)
        #pragma unroll
        for (int jn = 0; jn < 5; ++jn)
            o[it][jn] = (f32x4){0.f, 0.f, 0.f, 0.f};

    for (int kt = 0; kt <= qt; ++kt) {
        // ---- S = Q @ K^T over this 64-key tile ----
        bf16x8 kf[4][2];
        #pragma unroll
        for (int jt = 0; jt < 4; ++jt)
            #pragma unroll
            for (int kc = 0; kc < 2; ++kc)
                kf[jt][kc] = *(const bf16x8*)(Kb + ((kt * 64 + jt * 16 + mi) << 6) + kc * 32 + quad * 8);

        f32x4 s[4][4];
        #pragma unroll
        for (int it = 0; it < 4; ++it)
            #pragma unroll
            for (int jt = 0; jt < 4; ++jt)
                s[it][jt] = (f32x4){0.f, 0.f, 0.f, 0.f};
        #pragma unroll
        for (int kc = 0; kc < 2; ++kc)
            #pragma unroll
            for (int it = 0; it < 4; ++it)
                #pragma unroll
                for (int jt = 0; jt < 4; ++jt)
                    s[it][jt] = __builtin_amdgcn_mfma_f32_16x16x32_bf16(qf[it][kc], kf[jt][kc], s[it][jt], 0, 0, 0);

        // ---- mask (diagonal tile only) + exp -> P (bf16, LDS, [row][key] stride 72) ----
        const bool diag = (kt == qt);
        #pragma unroll
        for (int it = 0; it < 4; ++it)
            #pragma unroll
            for (int jt = 0; jt < 4; ++jt)
                #pragma unroll
                for (int r = 0; r < 4; ++r) {
                    int qrow = it * 16 + quad * 4 + r;
                    int kcol = jt * 16 + mi;
                    float e = __expf(s[it][jt][r]);
                    if (diag && kcol > qrow) e = 0.f;
                    P[qrow * 72 + kcol] = f2bf(e);
                }

        // ---- PV: o += P @ [V | 1]^T  (A-frags from LDS, B-frags from V^T global) ----
        bf16x8 pf[4][2];
        #pragma unroll
        for (int it = 0; it < 4; ++it)
            #pragma unroll
            for (int kc = 0; kc < 2; ++kc)
                pf[it][kc] = *(const bf16x8*)(P + (it * 16 + mi) * 72 + kc * 32 + quad * 8);

        bf16x8 vf[5][2];
        #pragma unroll
        for (int jn = 0; jn < 5; ++jn)
            #pragma unroll
            for (int kc = 0; kc < 2; ++kc)
                vf[jn][kc] = *(const bf16x8*)(Vt + (size_t)(jn * 16 + mi) * 256 + kt * 64 + kc * 32 + quad * 8);

        #pragma unroll
        for (int kc = 0; kc < 2; ++kc)
            #pragma unroll
            for (int it = 0; it < 4; ++it)
                #pragma unroll
                for (int jn = 0; jn < 5; ++jn)
                    o[it][jn] = __builtin_amdgcn_mfma_f32_16x16x32_bf16(pf[it][kc], vf[jn][kc], o[it][jn], 0, 0, 0);
    }

    // ---- epilogue A: l sits in n-tile 4 (ones row of V^T); normalize -> G bf16 in P ----
    #pragma unroll
    for (int it = 0; it < 4; ++it) {
        float inv[4];
        #pragma unroll
        for (int r = 0; r < 4; ++r) {
            float lv = __shfl(o[it][4][r], (lane & 48));   // from lane quad*16+0
            inv[r] = 1.0f / lv;
        }
        #pragma unroll
        for (int jn = 0; jn < 4; ++jn)
            #pragma unroll
            for (int r = 0; r < 4; ++r) {
                int row = it * 16 + quad * 4 + r;
                P[row * 72 + jn * 16 + mi] = f2bf(o[it][jn][r] * inv[r]);
            }
    }
    // wave-private LDS: compiler inserts lgkmcnt before dependent reads; no barrier.

    // ---- epilogue B: up-dense R = G @ Wup via MFMA (B-frags = WupT rows) ----
    bf16x8 ga[4][2], wf[4][2];
    #pragma unroll
    for (int it = 0; it < 4; ++it)
        #pragma unroll
        for (int kc = 0; kc < 2; ++kc)
            ga[it][kc] = *(const bf16x8*)(P + (it * 16 + mi) * 72 + kc * 32 + quad * 8);
    #pragma unroll
    for (int jn = 0; jn < 4; ++jn)
        #pragma unroll
        for (int kc = 0; kc < 2; ++kc)
            wf[jn][kc] = *(const bf16x8*)(WupT + (jn * 16 + mi) * 64 + kc * 32 + quad * 8);

    f32x4 u[4][4];
    #pragma unroll
    for (int it = 0; it < 4; ++it)
        #pragma unroll
        for (int jn = 0; jn < 4; ++jn)
            u[it][jn] = (f32x4){0.f, 0.f, 0.f, 0.f};
    #pragma unroll
    for (int kc = 0; kc < 2; ++kc)
        #pragma unroll
        for (int it = 0; it < 4; ++it)
            #pragma unroll
            for (int jn = 0; jn < 4; ++jn)
                u[it][jn] = __builtin_amdgcn_mfma_f32_16x16x32_bf16(ga[it][kc], wf[jn][kc], u[it][jn], 0, 0, 0);

    // ---- write ms[(b*256 + m) * 1024 + h*64 + dp] ----
    const int b = bh >> 4, h = bh & 15;
    #pragma unroll
    for (int jn = 0; jn < 4; ++jn) {
        const int dp = jn * 16 + mi;
        const float bv = bup[dp];
        #pragma unroll
        for (int it = 0; it < 4; ++it)
            #pragma unroll
            for (int r = 0; r < 4; ++r) {
                int m = qt * 64 + it * 16 + quad * 4 + r;
                ms[((size_t)(b * 256 + m) << 10) + h * 64 + dp] = f2bf(u[it][jn][r] + bv);
            }
    }
}

// ====== launch 4: final dense + fused 8x upsample, straight into d_out ======
// 1-wave 64x64 pipelined GEMM (K=1024, 16 steps); C-tile staged to padded LDS,
// then 8x-replicated coalesced float4 stores (no intermediate C buffer).
__global__ __launch_bounds__(64) void gemm_out_up(
    const u16* __restrict__ A, const u16* __restrict__ Bt,
    const float* __restrict__ bias, float* __restrict__ out)
{
    __shared__ __align__(16) u16 S[2][2][4096];
    __shared__ __align__(16) float Cs[64][68];    // pad 68: 16B-aligned rows

    const int lane = threadIdx.x;
    const int mi   = lane & 15;
    const int quad = lane >> 4;

    const int bid = blockIdx.x;                   // 0..255
    const int wg  = (bid & 7) * 32 + (bid >> 3);  // bijective XCD chunking (256 = 8*32)
    const int m0  = (wg >> 4) * 64;
    const int n0  = (wg & 15) * 64;

    const char* Ab = (const char*)A  + (size_t)m0 * 2048;
    const char* Bb = (const char*)Bt + (size_t)n0 * 2048;

    f32x4 acc[4][4];
    #pragma unroll
    for (int i = 0; i < 4; ++i)
        #pragma unroll
        for (int j = 0; j < 4; ++j)
            acc[i][j] = (f32x4){0.f, 0.f, 0.f, 0.f};

    stage64(Ab, 0, S[0][0], lane, 2048);
    stage64(Bb, 0, S[0][1], lane, 2048);

    #pragma unroll 1
    for (int t = 0; t < 16; ++t) {
        const int cur = t & 1;
        if (t < 15) {
            stage64(Ab, (size_t)(t + 1) * 128, S[cur ^ 1][0], lane, 2048);
            stage64(Bb, (size_t)(t + 1) * 128, S[cur ^ 1][1], lane, 2048);
            asm volatile("s_waitcnt vmcnt(16)" ::: "memory");
        } else {
            asm volatile("s_waitcnt vmcnt(0)" ::: "memory");
        }
        __builtin_amdgcn_sched_barrier(0);

        bf16x8 af[4][2], bf[4][2];
        frag_read(S[cur][0], mi, quad, af);
        frag_read(S[cur][1], mi, quad, bf);

        #pragma unroll
        for (int kc = 0; kc < 2; ++kc)
            #pragma unroll
            for (int i = 0; i < 4; ++i)
                #pragma unroll
                for (int j = 0; j < 4; ++j)
                    acc[i][j] = __builtin_amdgcn_mfma_f32_16x16x32_bf16(af[i][kc], bf[j][kc], acc[i][j], 0, 0, 0);
    }

    // C-tile (+bias) to LDS
    #pragma unroll
    for (int j = 0; j < 4; ++j) {
        const float bv = bias[n0 + j * 16 + mi];
        #pragma unroll
        for (int i = 0; i < 4; ++i)
            #pragma unroll
            for (int r = 0; r < 4; ++r)
                Cs[i * 16 + quad * 4 + r][j * 16 + mi] = acc[i][j][r] + bv;
    }

    // 8x broadcast write-out: 64 C-rows x 8 reps x 64 cols = 8192 float4
    // per iter: all lanes share one C-row (broadcast LDS read), 4 reps x 16 col4.
    const int col4 = lane & 15;
    #pragma unroll 4
    for (int it = 0; it < 128; ++it) {
        const int crow = it >> 1;
        const int rep  = ((it & 1) << 2) + (lane >> 4);
        float4 val = *(const float4*)&Cs[crow][col4 * 4];
        const int R = m0 + crow;
        const int b = R >> 8, tc = R & 255;
        float* po = out + (((size_t)((b << 11) + (tc << 3) + rep)) << 10) + n0 + (col4 << 2);
        *(float4*)po = val;
    }
}

extern "C" void kernel_launch(void* const* d_in, const int* in_sizes, int n_in,
                              void* d_out, int out_size, void* d_ws, size_t ws_size,
                              hipStream_t stream) {
    const float* q   = (const float*)d_in[0];
    const float* k   = (const float*)d_in[1];
    const float* v   = (const float*)d_in[2];
    const float* Wq  = (const float*)d_in[3];
    const float* bq  = (const float*)d_in[4];
    const float* Wk  = (const float*)d_in[5];
    const float* bk  = (const float*)d_in[6];
    const float* Wv  = (const float*)d_in[7];
    const float* bv  = (const float*)d_in[8];
    const float* Wup = (const float*)d_in[9];
    const float* bup = (const float*)d_in[10];
    const float* Wc  = (const float*)d_in[11];
    const float* bc  = (const float*)d_in[12];
    const float* wcq = (const float*)d_in[13];
    const float* bcq = (const float*)d_in[14];
    const float* wck = (const float*)d_in[15];
    const float* bck = (const float*)d_in[16];
    const float* wcv = (const float*)d_in[17];
    const float* bcv = (const float*)d_in[18];

    // A3 staging (18.9 MB bf16 [3][1024][3072]) lives in d_out; gemm_out_up
    // rewrites all of d_out at the end.
    u16* A3 = (u16*)d_out;

    char* wsb = (char*)d_ws;
    // ws layout (bytes):
    //   0        : Wt3  bf16 [3][1024 n][3072 k]  18,874,368
    //   18874368 : Wtc  bf16 [1024][1024]          2,097,152
    //   20971520 : biasT f32 [3][3][1024]             36,864
    //   21008384 : qb   bf16 [64*256][64]          2,097,152
    //   23105536 : kb   bf16 [64*256][64]          2,097,152
    //   25202688 : vt   bf16 [64][80][256]         2,621,440
    //   27824128 : WupT bf16 [64][64]                  8,192
    //   32018432 : ms   bf16 [1024][1024]          2,097,152
    u16*   Wt3   = (u16*)wsb;
    u16*   Wtc   = (u16*)(wsb + 18874368);
    float* biasT = (float*)(wsb + 20971520);
    u16*   qb    = (u16*)(wsb + 21008384);
    u16*   kb    = (u16*)(wsb + 23105536);
    u16*   vt    = (u16*)(wsb + 25202688);
    u16*   WupT  = (u16*)(wsb + 27824128);
    u16*   ms    = (u16*)(wsb + 32018432);

    // 1. weight prep + bias table + WupT + input staging (one dispatch)
    prep_stage<<<4109, 256, 0, stream>>>(q, k, v, Wq, Wk, Wv, Wc, Wup,
                                         wcq, wck, wcv, bcq, bck, bcv,
                                         bq, bk, bv, Wt3, Wtc, biasT, WupT, A3);
    // 2. fused QKV GEMM + V^T pad (784 one-wave blocks)
    gemm_qkv<<<784, 64, 0, stream>>>(A3, Wt3, biasT, qb, kb, vt);
    // 3. MFMA causal attention + fused up-dense -> ms (256 one-wave blocks)
    attn_mfma<<<dim3(4, 64), 64, 0, stream>>>(qb, kb, vt, WupT, bup, ms);
    // 4. final dense + fused 8x upsample -> d_out (256 one-wave blocks)
    gemm_out_up<<<256, 64, 0, stream>>>(ms, Wtc, bc, (float*)d_out);
}

// Round 8
// 241.355 us; speedup vs baseline: 1.1647x; 1.0094x over previous
//
#include <hip/hip_runtime.h>
#include <cstdint>
#include <cstddef>

// Problem constants
#define Bc  4
#define Sc  2048
#define Dc  1024
#define Hc  16
#define DDc 64
#define Nc  256   // pooled length

typedef unsigned short u16;
typedef unsigned int   u32;
typedef __bf16 bf16_t;
typedef bf16_t bf16x8 __attribute__((ext_vector_type(8)));
typedef float  f32x4  __attribute__((ext_vector_type(4)));

__device__ __forceinline__ u16 f2bf(float x) {
    u32 u = __float_as_uint(x);
    return (u16)((u + 0x7FFFu + ((u >> 16) & 1u)) >> 16);   // RNE
}
__device__ __forceinline__ u32 pack2(float a, float b) {
    return (u32)f2bf(a) | ((u32)f2bf(b) << 16);
}
__device__ __forceinline__ uint2 pack4v(f32x4 x) {
    return make_uint2(pack2(x[0], x[1]), pack2(x[2], x[3]));
}
__device__ __forceinline__ float bf2f(u16 x) {
    return __uint_as_float((u32)x << 16);
}

// async global->LDS, 16B per lane
__device__ __forceinline__ void gload_lds16(const void* gp, void* lp) {
    __builtin_amdgcn_global_load_lds(
        reinterpret_cast<const __attribute__((address_space(1))) void*>(
            reinterpret_cast<uintptr_t>(gp)),
        reinterpret_cast<__attribute__((address_space(3))) void*>(
            reinterpret_cast<uintptr_t>(lp)),
        16, 0, 0);
}

// ---- 1-wave GEMM building blocks (64x64 tile, BK=64, granule-swizzled LDS) ----
// Stage one 64-row x 128-byte K-slab into 8KB LDS. LDS slot (row r, granule g)
// receives global granule g ^ (r&7)  (8 granules of 16B per 128B row).
// Reader applies the same XOR -> bank-conflict-free, layout self-inverse.
__device__ __forceinline__ void stage64(const char* src, size_t kb, u16* lds,
                                        int lane, size_t rstride) {
    const int rowoff = lane >> 3;                       // 0..7
    const int srcg   = ((lane & 7) ^ (rowoff & 7)) * 16;
    const char* s0 = src + kb + (size_t)srcg;
    #pragma unroll
    for (int i = 0; i < 8; ++i)
        gload_lds16(s0 + (size_t)(8 * i + rowoff) * rstride,
                    (char*)lds + i * 1024);             // wave-uniform dest base
}

// Read 4x2 bf16x8 fragments (rows i*16+mi, K-halves kc) with the inverse XOR.
__device__ __forceinline__ void frag_read(const u16* lds, int mi, int quad,
                                          bf16x8 f[4][2]) {
    const int key = mi & 7;                             // (i*16+mi)&7 == mi&7
    #pragma unroll
    for (int i = 0; i < 4; ++i)
        #pragma unroll
        for (int kc = 0; kc < 2; ++kc) {
            int g = (kc * 4 + quad) ^ key;
            f[i][kc] = *(const bf16x8*)(lds + (i * 16 + mi) * 64 + g * 8);
        }
}

// ================= launch 1: prep + bias + WupT + stage, one dispatch =================
// blocks [0,1024)    : weight prep (z = bid>>8, k0 = ((bid>>4)&15)*64, n0 = (bid&15)*64)
// blocks [1024,1036) : bias table
// block  1036        : Wup transpose -> WupT bf16 [dp][d]
// blocks [1037,4109) : input staging (XCD-chunk swizzled)
__global__ __launch_bounds__(256) void prep_stage(
    const float* __restrict__ q,  const float* __restrict__ k,  const float* __restrict__ v,
    const float* __restrict__ Wq, const float* __restrict__ Wk,
    const float* __restrict__ Wv, const float* __restrict__ Wc,
    const float* __restrict__ Wup,
    const float* __restrict__ wcq, const float* __restrict__ wck, const float* __restrict__ wcv,
    const float* __restrict__ bcq, const float* __restrict__ bck, const float* __restrict__ bcv,
    const float* __restrict__ bq,  const float* __restrict__ bk,  const float* __restrict__ bv,
    u16* __restrict__ Wt3, u16* __restrict__ Wtc, float* __restrict__ biasT,
    u16* __restrict__ WupT, u16* __restrict__ A3)
{
    __shared__ float T[64][65];
    const int bid = blockIdx.x;
    const int tid = threadIdx.x;

    if (bid < 1024) {
        // ---------------- weight prep ----------------
        const int z = bid >> 8;
        const float* W = (z == 0) ? Wq : (z == 1) ? Wk : (z == 2) ? Wv : Wc;
        const int k0 = ((bid >> 4) & 15) * 64, n0 = (bid & 15) * 64;
        const int c = tid & 63, r4 = tid >> 6;
        #pragma unroll
        for (int i = 0; i < 16; ++i) {
            int r = i * 4 + r4;
            T[r][c] = W[(size_t)(k0 + r) * 1024 + n0 + c];
        }
        __syncthreads();
        if (z < 3) {
            const float* wc = (z == 0) ? wcq : (z == 1) ? wck : wcv;
            const float fs = 0.125f * ((z == 2) ? 1.0f : 0.35355339059327373f);
            u16* dst0 = Wt3 + (size_t)z * 3145728;
            #pragma unroll
            for (int i = 0; i < 16; ++i) {
                int r = i * 4 + r4;
                int n = n0 + r;
                float w0 = wc[n], w1 = wc[1024 + n], w2 = wc[2048 + n];
                float s2 = fs * w2, s1 = s2 + fs * w1, s0 = s1 + fs * w0;
                float x = T[c][r];
                u16* dst = dst0 + (size_t)n * 3072 + k0 + c;
                dst[0]    = f2bf(x * s0);
                dst[1024] = f2bf(x * s1);
                dst[2048] = f2bf(x * s2);
            }
        } else {
            #pragma unroll
            for (int i = 0; i < 16; ++i) {
                int r = i * 4 + r4;
                Wtc[(size_t)(n0 + r) * 1024 + k0 + c] = f2bf(T[c][r]);
            }
        }
        return;
    }

    if (bid < 1036) {
        // ---------------- bias table: biasT[z][j][c], j = min(t,2) ----------------
        int gid = (bid - 1024) * 256 + tid;   // over 3*1024
        int c = gid & 1023, z = gid >> 10;
        const float* wc    = (z == 0) ? wcq : (z == 1) ? wck : wcv;
        const float* bconv = (z == 0) ? bcq : (z == 1) ? bck : bcv;
        const float* bl    = (z == 0) ? bq  : (z == 1) ? bk  : bv;
        const float nrm = (z == 2) ? 1.0f : 0.35355339059327373f;
        float w0 = wc[c], w1 = wc[1024 + c], w2 = wc[2048 + c];
        float bc_ = bconv[c], bl_ = bl[c];
        float* dst = biasT + (size_t)z * 3072 + c;
        dst[0]    = 0.125f * (bc_ + nrm * bl_ * w2);
        dst[1024] = 0.125f * (8.f * bc_ + nrm * bl_ * (7.f * w0 + 8.f * w1 + 8.f * w2));
        dst[2048] = 0.125f * (8.f * bc_ + nrm * bl_ * 8.f * (w0 + w1 + w2));
        return;
    }

    if (bid == 1036) {
        // ---------------- Wup transpose: WupT[dp][d] = Wup[d][dp], bf16 ----------------
        const int c = tid & 63, r4 = tid >> 6;
        #pragma unroll
        for (int i = 0; i < 16; ++i) {
            int r = i * 4 + r4;
            T[r][c] = Wup[r * 64 + c];
        }
        __syncthreads();
        #pragma unroll
        for (int i = 0; i < 16; ++i) {
            int r = i * 4 + r4;
            WupT[r * 64 + c] = f2bf(T[c][r]);
        }
        return;
    }

    // ---------------- staging: differenced sections, K-concatenated ----------------
    // Thread t loads 10 contiguous rows [8t-9 .. 8t] (one f32x4 column slice):
    //   A0[t] = sum rows 8t-9..8t-2 ; B1[t] = x[8t-1]-x[8t-9] ; B2[t] = x[8t]-x[8t-8]
    // Named registers + asm ballast with "+v" on ALL 10 values: hard data dep forces
    // all 10 loads in flight simultaneously (r6/r7: sched_barrier failed, VGPR stuck
    // at 32 -> loads serialized at 2.2 TB/s; IR passes hoisted the adds past the hint).
    int sbid0 = bid - 1037;                             // 0..3071
    int sbid  = (sbid0 & 7) * 384 + (sbid0 >> 3);       // bijective (3072 = 8*384)
    int gid = sbid * 256 + tid;                         // over 3 * 2^18 float4-groups
    int c4 = gid & 255, t = (gid >> 8) & 255, b = (gid >> 16) & 3, inp = gid >> 18;
    const float* src = (inp == 0) ? q : (inp == 1) ? k : v;
    const f32x4* X4 = (const f32x4*)(src + (size_t)b * Sc * Dc) + c4
                      + ((ptrdiff_t)(t << 3) - 9) * 256;   // row 8t-9

    const f32x4 zz = (f32x4){0.f, 0.f, 0.f, 0.f};
    f32x4 r0, r1, r2, r3, r4, r5, r6, r7, r8, r9;
    if (t >= 2) {
        r0 = X4[0 * 256]; r1 = X4[1 * 256]; r2 = X4[2 * 256]; r3 = X4[3 * 256];
        r4 = X4[4 * 256]; r5 = X4[5 * 256]; r6 = X4[6 * 256]; r7 = X4[7 * 256];
        r8 = X4[8 * 256]; r9 = X4[9 * 256];
    } else if (t == 1) {
        r0 = zz;
        r1 = X4[1 * 256]; r2 = X4[2 * 256]; r3 = X4[3 * 256];
        r4 = X4[4 * 256]; r5 = X4[5 * 256]; r6 = X4[6 * 256]; r7 = X4[7 * 256];
        r8 = X4[8 * 256]; r9 = X4[9 * 256];
    } else {
        r0 = zz; r1 = zz; r2 = zz; r3 = zz; r4 = zz;
        r5 = zz; r6 = zz; r7 = zz; r8 = zz;
        r9 = X4[9 * 256];
    }
    // ballast: all 10 values must be materialized in VGPRs here
    asm volatile("" : "+v"(r0), "+v"(r1), "+v"(r2), "+v"(r3), "+v"(r4),
                      "+v"(r5), "+v"(r6), "+v"(r7), "+v"(r8), "+v"(r9));

    f32x4 A0 = ((r0 + r1) + (r2 + r3)) + ((r4 + r5) + (r6 + r7));
    f32x4 B1 = r8 - r0;
    f32x4 B2 = r9 - r1;

    size_t s0 = (size_t)inp * 3145728 + (size_t)(b * 256 + t) * 3072 + c4 * 4;
    *(uint2*)(A3 + s0)        = pack4v(A0);
    *(uint2*)(A3 + s0 + 1024) = pack4v(B1);
    *(uint2*)(A3 + s0 + 2048) = pack4v(B2);
}

// ====== launch 2: fused QKV GEMM + V^T pad, [1024 x 3072] @ Wt3_z^T + biasT ======
// blocks [0,768): 1-wave 64x64-tile GEMM (counted-vmcnt double-buffer, XCD swizzle)
// blocks [768,784): V^T pad rows 64..79 (row 64 = 1.0 softmax-l trick, rest 0)
__global__ __launch_bounds__(64) void gemm_qkv(
    const u16* __restrict__ A3, const u16* __restrict__ Wt3,
    const float* __restrict__ biasT,
    u16* __restrict__ qb, u16* __restrict__ kb, u16* __restrict__ vt)
{
    __shared__ __align__(16) u16 S[2][2][4096];   // [buf][A|B][64*64]

    const int lane = threadIdx.x;
    const int bid = blockIdx.x;

    if (bid >= 768) {
        // ---- vpad: 4 bh per block ----
        const int vb = bid - 768;                 // 0..15
        #pragma unroll
        for (int bh4 = 0; bh4 < 4; ++bh4) {
            const int bh = vb * 4 + bh4;
            #pragma unroll
            for (int it = 0; it < 8; ++it) {
                int gidx = it * 64 + lane;        // 512 uint4 per bh
                int row  = 64 + (gidx >> 5);
                int c0   = (gidx & 31) * 8;
                u32 fill = (row == 64) ? 0x3F803F80u : 0u;
                *(uint4*)(vt + (size_t)bh * 20480 + (size_t)row * 256 + c0) =
                    make_uint4(fill, fill, fill, fill);
            }
        }
        return;
    }

    const int mi   = lane & 15;
    const int quad = lane >> 4;

    const int wg  = (bid & 7) * 96 + (bid >> 3);  // bijective XCD chunking (768 = 8*96)
    const int z   = wg >> 8;
    const int m0  = ((wg >> 4) & 15) * 64;
    const int n0  = (wg & 15) * 64;

    const char* Ab = (const char*)(A3  + (size_t)z * 3145728) + (size_t)m0 * 6144;
    const char* Bb = (const char*)(Wt3 + (size_t)z * 3145728) + (size_t)n0 * 6144;

    f32x4 acc[4][4];
    #pragma unroll
    for (int i = 0; i < 4; ++i)
        #pragma unroll
        for (int j = 0; j < 4; ++j)
            acc[i][j] = (f32x4){0.f, 0.f, 0.f, 0.f};

    stage64(Ab, 0, S[0][0], lane, 6144);
    stage64(Bb, 0, S[0][1], lane, 6144);

    #pragma unroll 1
    for (int t = 0; t < 48; ++t) {
        const int cur = t & 1;
        if (t < 47) {
            stage64(Ab, (size_t)(t + 1) * 128, S[cur ^ 1][0], lane, 6144);
            stage64(Bb, (size_t)(t + 1) * 128, S[cur ^ 1][1], lane, 6144);
            asm volatile("s_waitcnt vmcnt(16)" ::: "memory");   // cur's 16 done, next 16 in flight
        } else {
            asm volatile("s_waitcnt vmcnt(0)" ::: "memory");
        }
        __builtin_amdgcn_sched_barrier(0);

        bf16x8 af[4][2], bf[4][2];
        frag_read(S[cur][0], mi, quad, af);
        frag_read(S[cur][1], mi, quad, bf);

        #pragma unroll
        for (int kc = 0; kc < 2; ++kc)
            #pragma unroll
            for (int i = 0; i < 4; ++i)
                #pragma unroll
                for (int j = 0; j < 4; ++j)
                    acc[i][j] = __builtin_amdgcn_mfma_f32_16x16x32_bf16(af[i][kc], bf[j][kc], acc[i][j], 0, 0, 0);
    }

    const float* bT = biasT + (size_t)z * 3072;
    if (z == 2) {
        #pragma unroll
        for (int j = 0; j < 4; ++j) {
            const int col = n0 + j * 16 + mi;
            const int h = col >> 6, d = col & 63;
            #pragma unroll
            for (int i = 0; i < 4; ++i) {
                const int row = m0 + i * 16 + quad * 4;
                const int b = row >> 8, t0 = row & 255;
                const int bh = b * 16 + h;
                u16 w[4];
                #pragma unroll
                for (int r = 0; r < 4; ++r) {
                    int t = t0 + r;
                    w[r] = f2bf(acc[i][j][r] + bT[(t < 2 ? t : 2) * 1024 + col]);
                }
                *(uint2*)(vt + (size_t)bh * 20480 + (size_t)d * 256 + t0) =
                    make_uint2((u32)w[0] | ((u32)w[1] << 16), (u32)w[2] | ((u32)w[3] << 16));
            }
        }
    } else {
        u16* dst = z ? kb : qb;
        #pragma unroll
        for (int j = 0; j < 4; ++j) {
            const int col = n0 + j * 16 + mi;
            const int h = col >> 6, d = col & 63;
            #pragma unroll
            for (int i = 0; i < 4; ++i) {
                const int row = m0 + i * 16 + quad * 4;
                const int b = row >> 8;
                const int bh = b * 16 + h;
                #pragma unroll
                for (int r = 0; r < 4; ++r) {
                    int t = (row & 255) + r;
                    dst[(((size_t)bh * 256 + t) << 6) + d] =
                        f2bf(acc[i][j][r] + bT[(t < 2 ? t : 2) * 1024 + col]);
                }
            }
        }
    }
}

// ---------------- launch 3: MFMA causal attention + fused up-dense ----------------
// One block per (qt, bh): 1 wave. After online attention, normalize -> G bf16 in P
// LDS -> MFMA against WupT + bup -> ms directly (updense kernel deleted).
__global__ __launch_bounds__(64) void attn_mfma(
    const u16* __restrict__ qb, const u16* __restrict__ kb,
    const u16* __restrict__ vt, const u16* __restrict__ WupT,
    const float* __restrict__ bup, u16* __restrict__ ms)
{
    __shared__ __align__(16) u16 P[64 * 72];    // stride 72 u16: 2-way banks only
    const int qt   = blockIdx.x;
    const int bh   = blockIdx.y;
    const int lane = threadIdx.x;
    const int mi   = lane & 15;
    const int quad = lane >> 4;

    const u16* Qb = qb + (((size_t)bh * 256 + qt * 64) << 6);
    const u16* Kb = kb + ((size_t)bh << 14);        // *256*64
    const u16* Vt = vt + (size_t)bh * 80 * 256;

    // Q fragments (persist across key tiles): A[m=mi][k=quad*8+j]
    bf16x8 qf[4][2];
    #pragma unroll
    for (int it = 0; it < 4; ++it)
        #pragma unroll
        for (int kc = 0; kc < 2; ++kc)
            qf[it][kc] = *(const bf16x8*)(Qb + ((it * 16 + mi) << 6) + kc * 32 + quad * 8);

    f32x4 o[4][5];
    #pragma unroll
    for (int it = 0; it < 4; ++it)
        #pragma unroll
        for (int jn = 0; jn < 5; ++jn)
            o[it][jn] = (f32x4){0.f, 0.f, 0.f, 0.f};

    for (int kt = 0; kt <= qt; ++kt) {
        // ---- S = Q @ K^T over this 64-key tile ----
        bf16x8 kf[4][2];
        #pragma unroll
        for (int jt = 0; jt < 4; ++jt)
            #pragma unroll
            for (int kc = 0; kc < 2; ++kc)
                kf[jt][kc] = *(const bf16x8*)(Kb + ((kt * 64 + jt * 16 + mi) << 6) + kc * 32 + quad * 8);

        f32x4 s[4][4];
        #pragma unroll
        for (int it = 0; it < 4; ++it)
            #pragma unroll
            for (int jt = 0; jt < 4; ++jt)
                s[it][jt] = (f32x4){0.f, 0.f, 0.f, 0.f};
        #pragma unroll
        for (int kc = 0; kc < 2; ++kc)
            #pragma unroll
            for (int it = 0; it < 4; ++it)
                #pragma unroll
                for (int jt = 0; jt < 4; ++jt)
                    s[it][jt] = __builtin_amdgcn_mfma_f32_16x16x32_bf16(qf[it][kc], kf[jt][kc], s[it][jt], 0, 0, 0);

        // ---- mask (diagonal tile only) + exp -> P (bf16, LDS, [row][key] stride 72) ----
        const bool diag = (kt == qt);
        #pragma unroll
        for (int it = 0; it < 4; ++it)
            #pragma unroll
            for (int jt = 0; jt < 4; ++jt)
                #pragma unroll
                for (int r = 0; r < 4; ++r) {
                    int qrow = it * 16 + quad * 4 + r;
                    int kcol = jt * 16 + mi;
                    float e = __expf(s[it][jt][r]);
                    if (diag && kcol > qrow) e = 0.f;
                    P[qrow * 72 + kcol] = f2bf(e);
                }

        // ---- PV: o += P @ [V | 1]^T  (A-frags from LDS, B-frags from V^T global) ----
        bf16x8 pf[4][2];
        #pragma unroll
        for (int it = 0; it < 4; ++it)
            #pragma unroll
            for (int kc = 0; kc < 2; ++kc)
                pf[it][kc] = *(const bf16x8*)(P + (it * 16 + mi) * 72 + kc * 32 + quad * 8);

        bf16x8 vf[5][2];
        #pragma unroll
        for (int jn = 0; jn < 5; ++jn)
            #pragma unroll
            for (int kc = 0; kc < 2; ++kc)
                vf[jn][kc] = *(const bf16x8*)(Vt + (size_t)(jn * 16 + mi) * 256 + kt * 64 + kc * 32 + quad * 8);

        #pragma unroll
        for (int kc = 0; kc < 2; ++kc)
            #pragma unroll
            for (int it = 0; it < 4; ++it)
                #pragma unroll
                for (int jn = 0; jn < 5; ++jn)
                    o[it][jn] = __builtin_amdgcn_mfma_f32_16x16x32_bf16(pf[it][kc], vf[jn][kc], o[it][jn], 0, 0, 0);
    }

    // ---- epilogue A: l sits in n-tile 4 (ones row of V^T); normalize -> G bf16 in P ----
    #pragma unroll
    for (int it = 0; it < 4; ++it) {
        float inv[4];
        #pragma unroll
        for (int r = 0; r < 4; ++r) {
            float lv = __shfl(o[it][4][r], (lane & 48));   // from lane quad*16+0
            inv[r] = 1.0f / lv;
        }
        #pragma unroll
        for (int jn = 0; jn < 4; ++jn)
            #pragma unroll
            for (int r = 0; r < 4; ++r) {
                int row = it * 16 + quad * 4 + r;
                P[row * 72 + jn * 16 + mi] = f2bf(o[it][jn][r] * inv[r]);
            }
    }
    // wave-private LDS: compiler inserts lgkmcnt before dependent reads; no barrier.

    // ---- epilogue B: up-dense R = G @ Wup via MFMA (B-frags = WupT rows) ----
    bf16x8 ga[4][2], wf[4][2];
    #pragma unroll
    for (int it = 0; it < 4; ++it)
        #pragma unroll
        for (int kc = 0; kc < 2; ++kc)
            ga[it][kc] = *(const bf16x8*)(P + (it * 16 + mi) * 72 + kc * 32 + quad * 8);
    #pragma unroll
    for (int jn = 0; jn < 4; ++jn)
        #pragma unroll
        for (int kc = 0; kc < 2; ++kc)
            wf[jn][kc] = *(const bf16x8*)(WupT + (jn * 16 + mi) * 64 + kc * 32 + quad * 8);

    f32x4 u[4][4];
    #pragma unroll
    for (int it = 0; it < 4; ++it)
        #pragma unroll
        for (int jn = 0; jn < 4; ++jn)
            u[it][jn] = (f32x4){0.f, 0.f, 0.f, 0.f};
    #pragma unroll
    for (int kc = 0; kc < 2; ++kc)
        #pragma unroll
        for (int it = 0; it < 4; ++it)
            #pragma unroll
            for (int jn = 0; jn < 4; ++jn)
                u[it][jn] = __builtin_amdgcn_mfma_f32_16x16x32_bf16(ga[it][kc], wf[jn][kc], u[it][jn], 0, 0, 0);

    // ---- write ms[(b*256 + m) * 1024 + h*64 + dp] ----
    const int b = bh >> 4, h = bh & 15;
    #pragma unroll
    for (int jn = 0; jn < 4; ++jn) {
        const int dp = jn * 16 + mi;
        const float bv = bup[dp];
        #pragma unroll
        for (int it = 0; it < 4; ++it)
            #pragma unroll
            for (int r = 0; r < 4; ++r) {
                int m = qt * 64 + it * 16 + quad * 4 + r;
                ms[((size_t)(b * 256 + m) << 10) + h * 64 + dp] = f2bf(u[it][jn][r] + bv);
            }
    }
}

// ====== launch 4: final dense + fused 8x upsample, straight into d_out ======
// 1-wave 64x64 pipelined GEMM (K=1024, 16 steps); C-tile staged to padded LDS,
// then 8x-replicated coalesced float4 stores (no intermediate C buffer).
__global__ __launch_bounds__(64) void gemm_out_up(
    const u16* __restrict__ A, const u16* __restrict__ Bt,
    const float* __restrict__ bias, float* __restrict__ out)
{
    __shared__ __align__(16) u16 S[2][2][4096];
    __shared__ __align__(16) float Cs[64][68];    // pad 68: 16B-aligned rows

    const int lane = threadIdx.x;
    const int mi   = lane & 15;
    const int quad = lane >> 4;

    const int bid = blockIdx.x;                   // 0..255
    const int wg  = (bid & 7) * 32 + (bid >> 3);  // bijective XCD chunking (256 = 8*32)
    const int m0  = (wg >> 4) * 64;
    const int n0  = (wg & 15) * 64;

    const char* Ab = (const char*)A  + (size_t)m0 * 2048;
    const char* Bb = (const char*)Bt + (size_t)n0 * 2048;

    f32x4 acc[4][4];
    #pragma unroll
    for (int i = 0; i < 4; ++i)
        #pragma unroll
        for (int j = 0; j < 4; ++j)
            acc[i][j] = (f32x4){0.f, 0.f, 0.f, 0.f};

    stage64(Ab, 0, S[0][0], lane, 2048);
    stage64(Bb, 0, S[0][1], lane, 2048);

    #pragma unroll 1
    for (int t = 0; t < 16; ++t) {
        const int cur = t & 1;
        if (t < 15) {
            stage64(Ab, (size_t)(t + 1) * 128, S[cur ^ 1][0], lane, 2048);
            stage64(Bb, (size_t)(t + 1) * 128, S[cur ^ 1][1], lane, 2048);
            asm volatile("s_waitcnt vmcnt(16)" ::: "memory");
        } else {
            asm volatile("s_waitcnt vmcnt(0)" ::: "memory");
        }
        __builtin_amdgcn_sched_barrier(0);

        bf16x8 af[4][2], bf[4][2];
        frag_read(S[cur][0], mi, quad, af);
        frag_read(S[cur][1], mi, quad, bf);

        #pragma unroll
        for (int kc = 0; kc < 2; ++kc)
            #pragma unroll
            for (int i = 0; i < 4; ++i)
                #pragma unroll
                for (int j = 0; j < 4; ++j)
                    acc[i][j] = __builtin_amdgcn_mfma_f32_16x16x32_bf16(af[i][kc], bf[j][kc], acc[i][j], 0, 0, 0);
    }

    // C-tile (+bias) to LDS
    #pragma unroll
    for (int j = 0; j < 4; ++j) {
        const float bv = bias[n0 + j * 16 + mi];
        #pragma unroll
        for (int i = 0; i < 4; ++i)
            #pragma unroll
            for (int r = 0; r < 4; ++r)
                Cs[i * 16 + quad * 4 + r][j * 16 + mi] = acc[i][j][r] + bv;
    }

    // 8x broadcast write-out: 64 C-rows x 8 reps x 64 cols = 8192 float4
    // per iter: all lanes share one C-row (broadcast LDS read), 4 reps x 16 col4.
    const int col4 = lane & 15;
    #pragma unroll 4
    for (int it = 0; it < 128; ++it) {
        const int crow = it >> 1;
        const int rep  = ((it & 1) << 2) + (lane >> 4);
        float4 val = *(const float4*)&Cs[crow][col4 * 4];
        const int R = m0 + crow;
        const int b = R >> 8, tc = R & 255;
        float* po = out + (((size_t)((b << 11) + (tc << 3) + rep)) << 10) + n0 + (col4 << 2);
        *(float4*)po = val;
    }
}

extern "C" void kernel_launch(void* const* d_in, const int* in_sizes, int n_in,
                              void* d_out, int out_size, void* d_ws, size_t ws_size,
                              hipStream_t stream) {
    const float* q   = (const float*)d_in[0];
    const float* k   = (const float*)d_in[1];
    const float* v   = (const float*)d_in[2];
    const float* Wq  = (const float*)d_in[3];
    const float* bq  = (const float*)d_in[4];
    const float* Wk  = (const float*)d_in[5];
    const float* bk  = (const float*)d_in[6];
    const float* Wv  = (const float*)d_in[7];
    const float* bv  = (const float*)d_in[8];
    const float* Wup = (const float*)d_in[9];
    const float* bup = (const float*)d_in[10];
    const float* Wc  = (const float*)d_in[11];
    const float* bc  = (const float*)d_in[12];
    const float* wcq = (const float*)d_in[13];
    const float* bcq = (const float*)d_in[14];
    const float* wck = (const float*)d_in[15];
    const float* bck = (const float*)d_in[16];
    const float* wcv = (const float*)d_in[17];
    const float* bcv = (const float*)d_in[18];

    // A3 staging (18.9 MB bf16 [3][1024][3072]) lives in d_out; gemm_out_up
    // rewrites all of d_out at the end.
    u16* A3 = (u16*)d_out;

    char* wsb = (char*)d_ws;
    // ws layout (bytes):
    //   0        : Wt3  bf16 [3][1024 n][3072 k]  18,874,368
    //   18874368 : Wtc  bf16 [1024][1024]          2,097,152
    //   20971520 : biasT f32 [3][3][1024]             36,864
    //   21008384 : qb   bf16 [64*256][64]          2,097,152
    //   23105536 : kb   bf16 [64*256][64]          2,097,152
    //   25202688 : vt   bf16 [64][80][256]         2,621,440
    //   27824128 : WupT bf16 [64][64]                  8,192
    //   32018432 : ms   bf16 [1024][1024]          2,097,152
    u16*   Wt3   = (u16*)wsb;
    u16*   Wtc   = (u16*)(wsb + 18874368);
    float* biasT = (float*)(wsb + 20971520);
    u16*   qb    = (u16*)(wsb + 21008384);
    u16*   kb    = (u16*)(wsb + 23105536);
    u16*   vt    = (u16*)(wsb + 25202688);
    u16*   WupT  = (u16*)(wsb + 27824128);
    u16*   ms    = (u16*)(wsb + 32018432);

    // 1. weight prep + bias table + WupT + input staging (one dispatch)
    prep_stage<<<4109, 256, 0, stream>>>(q, k, v, Wq, Wk, Wv, Wc, Wup,
                                         wcq, wck, wcv, bcq, bck, bcv,
                                         bq, bk, bv, Wt3, Wtc, biasT, WupT, A3);
    // 2. fused QKV GEMM + V^T pad (784 one-wave blocks)
    gemm_qkv<<<784, 64, 0, stream>>>(A3, Wt3, biasT, qb, kb, vt);
    // 3. MFMA causal attention + fused up-dense -> ms (256 one-wave blocks)
    attn_mfma<<<dim3(4, 64), 64, 0, stream>>>(qb, kb, vt, WupT, bup, ms);
    // 4. final dense + fused 8x upsample -> d_out (256 one-wave blocks)
    gemm_out_up<<<256, 64, 0, stream>>>(ms, Wtc, bc, (float*)d_out);
}

// Round 9
// 241.006 us; speedup vs baseline: 1.1663x; 1.0014x over previous
//
#include <hip/hip_runtime.h>
#include <cstdint>
#include <cstddef>

// Problem constants
#define Bc  4
#define Sc  2048
#define Dc  1024
#define Hc  16
#define DDc 64
#define Nc  256   // pooled length

typedef unsigned short u16;
typedef unsigned int   u32;
typedef __bf16 bf16_t;
typedef bf16_t bf16x8 __attribute__((ext_vector_type(8)));
typedef float  f32x4  __attribute__((ext_vector_type(4)));

__device__ __forceinline__ u16 f2bf(float x) {
    u32 u = __float_as_uint(x);
    return (u16)((u + 0x7FFFu + ((u >> 16) & 1u)) >> 16);   // RNE
}
__device__ __forceinline__ u32 pack2(float a, float b) {
    return (u32)f2bf(a) | ((u32)f2bf(b) << 16);
}
__device__ __forceinline__ uint2 pack4v(f32x4 x) {
    return make_uint2(pack2(x[0], x[1]), pack2(x[2], x[3]));
}
__device__ __forceinline__ float bf2f(u16 x) {
    return __uint_as_float((u32)x << 16);
}

// async global->LDS, 16B per lane (global src per-lane; LDS dest wave-uniform value)
__device__ __forceinline__ void gload_lds16(const void* gp, void* lp) {
    __builtin_amdgcn_global_load_lds(
        reinterpret_cast<const __attribute__((address_space(1))) void*>(
            reinterpret_cast<uintptr_t>(gp)),
        reinterpret_cast<__attribute__((address_space(3))) void*>(
            reinterpret_cast<uintptr_t>(lp)),
        16, 0, 0);
}

// ---- 1-wave GEMM building blocks (64x64 tile, BK=64, granule-swizzled LDS) ----
// Stage one 64-row x 128-byte K-slab into 8KB LDS. LDS slot (row r, granule g)
// receives global granule g ^ (r&7)  (8 granules of 16B per 128B row).
// Reader applies the same XOR -> bank-conflict-free, layout self-inverse.
__device__ __forceinline__ void stage64(const char* src, size_t kb, u16* lds,
                                        int lane, size_t rstride) {
    const int rowoff = lane >> 3;                       // 0..7
    const int srcg   = ((lane & 7) ^ (rowoff & 7)) * 16;
    const char* s0 = src + kb + (size_t)srcg;
    #pragma unroll
    for (int i = 0; i < 8; ++i)
        gload_lds16(s0 + (size_t)(8 * i + rowoff) * rstride,
                    (char*)lds + i * 1024);             // wave-uniform dest base
}

// Read 4x2 bf16x8 fragments (rows i*16+mi, K-halves kc) with the inverse XOR.
__device__ __forceinline__ void frag_read(const u16* lds, int mi, int quad,
                                          bf16x8 f[4][2]) {
    const int key = mi & 7;                             // (i*16+mi)&7 == mi&7
    #pragma unroll
    for (int i = 0; i < 4; ++i)
        #pragma unroll
        for (int kc = 0; kc < 2; ++kc) {
            int g = (kc * 4 + quad) ^ key;
            f[i][kc] = *(const bf16x8*)(lds + (i * 16 + mi) * 64 + g * 8);
        }
}

// ================= launch 1: prep + bias + WupT + stage, one dispatch =================
// blocks [0,1024)    : weight prep (z = bid>>8, k0 = ((bid>>4)&15)*64, n0 = (bid&15)*64)
// blocks [1024,1036) : bias table
// block  1036        : Wup transpose -> WupT bf16 [dp][d]
// blocks [1037,4109) : input staging -- one block per (inp,b,t), 10 rows via
//                      global_load_lds into 40KB LDS (async DMA: all 10 row-loads
//                      in flight, no VGPR constraint -- r7/r8 showed regalloc
//                      refuses to batch register loads, VGPR stuck at 32 / 2.2 TB/s)
__global__ __launch_bounds__(256) void prep_stage(
    const float* __restrict__ q,  const float* __restrict__ k,  const float* __restrict__ v,
    const float* __restrict__ Wq, const float* __restrict__ Wk,
    const float* __restrict__ Wv, const float* __restrict__ Wc,
    const float* __restrict__ Wup,
    const float* __restrict__ wcq, const float* __restrict__ wck, const float* __restrict__ wcv,
    const float* __restrict__ bcq, const float* __restrict__ bck, const float* __restrict__ bcv,
    const float* __restrict__ bq,  const float* __restrict__ bk,  const float* __restrict__ bv,
    u16* __restrict__ Wt3, u16* __restrict__ Wtc, float* __restrict__ biasT,
    u16* __restrict__ WupT, u16* __restrict__ A3)
{
    __shared__ __align__(16) float LS[10 * 1024];   // 40KB: rows[10][1024] / T[64][65]
    float (*T)[65] = (float(*)[65])LS;
    const int bid = blockIdx.x;
    const int tid = threadIdx.x;

    if (bid < 1024) {
        // ---------------- weight prep ----------------
        const int z = bid >> 8;
        const float* W = (z == 0) ? Wq : (z == 1) ? Wk : (z == 2) ? Wv : Wc;
        const int k0 = ((bid >> 4) & 15) * 64, n0 = (bid & 15) * 64;
        const int c = tid & 63, r4 = tid >> 6;
        #pragma unroll
        for (int i = 0; i < 16; ++i) {
            int r = i * 4 + r4;
            T[r][c] = W[(size_t)(k0 + r) * 1024 + n0 + c];
        }
        __syncthreads();
        if (z < 3) {
            const float* wc = (z == 0) ? wcq : (z == 1) ? wck : wcv;
            const float fs = 0.125f * ((z == 2) ? 1.0f : 0.35355339059327373f);
            u16* dst0 = Wt3 + (size_t)z * 3145728;
            #pragma unroll
            for (int i = 0; i < 16; ++i) {
                int r = i * 4 + r4;
                int n = n0 + r;
                float w0 = wc[n], w1 = wc[1024 + n], w2 = wc[2048 + n];
                float s2 = fs * w2, s1 = s2 + fs * w1, s0 = s1 + fs * w0;
                float x = T[c][r];
                u16* dst = dst0 + (size_t)n * 3072 + k0 + c;
                dst[0]    = f2bf(x * s0);
                dst[1024] = f2bf(x * s1);
                dst[2048] = f2bf(x * s2);
            }
        } else {
            #pragma unroll
            for (int i = 0; i < 16; ++i) {
                int r = i * 4 + r4;
                Wtc[(size_t)(n0 + r) * 1024 + k0 + c] = f2bf(T[c][r]);
            }
        }
        return;
    }

    if (bid < 1036) {
        // ---------------- bias table: biasT[z][j][c], j = min(t,2) ----------------
        int gid = (bid - 1024) * 256 + tid;   // over 3*1024
        int c = gid & 1023, z = gid >> 10;
        const float* wc    = (z == 0) ? wcq : (z == 1) ? wck : wcv;
        const float* bconv = (z == 0) ? bcq : (z == 1) ? bck : bcv;
        const float* bl    = (z == 0) ? bq  : (z == 1) ? bk  : bv;
        const float nrm = (z == 2) ? 1.0f : 0.35355339059327373f;
        float w0 = wc[c], w1 = wc[1024 + c], w2 = wc[2048 + c];
        float bc_ = bconv[c], bl_ = bl[c];
        float* dst = biasT + (size_t)z * 3072 + c;
        dst[0]    = 0.125f * (bc_ + nrm * bl_ * w2);
        dst[1024] = 0.125f * (8.f * bc_ + nrm * bl_ * (7.f * w0 + 8.f * w1 + 8.f * w2));
        dst[2048] = 0.125f * (8.f * bc_ + nrm * bl_ * 8.f * (w0 + w1 + w2));
        return;
    }

    if (bid == 1036) {
        // ---------------- Wup transpose: WupT[dp][d] = Wup[d][dp], bf16 ----------------
        const int c = tid & 63, r4 = tid >> 6;
        #pragma unroll
        for (int i = 0; i < 16; ++i) {
            int r = i * 4 + r4;
            T[r][c] = Wup[r * 64 + c];
        }
        __syncthreads();
        #pragma unroll
        for (int i = 0; i < 16; ++i) {
            int r = i * 4 + r4;
            WupT[r * 64 + c] = f2bf(T[c][r]);
        }
        return;
    }

    // ---------------- staging: one block per (inp,b,t), all 1024 channels ----------------
    //   A0[t] = sum rows 8t-9..8t-2 ; B1[t] = x[8t-1]-x[8t-9] ; B2[t] = x[8t]-x[8t-8]
    // 10 rows (40KB) -> LDS via async global_load_lds; one barrier; LDS consume.
    int sbid0 = bid - 1037;                             // 0..3071
    int sbid  = (sbid0 & 7) * 384 + (sbid0 >> 3);       // bijective XCD chunk (3072=8*384)
    int t = sbid & 255, b = (sbid >> 8) & 3, inp = sbid >> 10;
    const float* src = (inp == 0) ? q : (inp == 1) ? k : v;
    const char* base = (const char*)(src + (size_t)b * Sc * Dc);   // + row*4096 bytes
    const int tid16 = tid * 16;
    const int wvoff = (tid & 192) * 16;                 // (tid>>6)*1024, wave-uniform value
    char* LSB = (char*)LS;

    const int nneg = (t >= 2) ? 0 : (t == 1 ? 1 : 9);   // missing (negative) rows
    const f32x4 zz = (f32x4){0.f, 0.f, 0.f, 0.f};
    for (int i = 0; i < nneg; ++i)                      // zero-fill missing rows
        *(f32x4*)(LSB + i * 4096 + tid16) = zz;
    #pragma unroll
    for (int i = 0; i < 10; ++i)                        // async DMA the valid rows
        if (i >= nneg)
            gload_lds16(base + (size_t)(8 * t - 9 + i) * 4096 + tid16,
                        LSB + i * 4096 + wvoff);
    __syncthreads();                                    // drains vmcnt + lgkmcnt

    f32x4 rr[10];
    #pragma unroll
    for (int i = 0; i < 10; ++i)
        rr[i] = *(const f32x4*)(LSB + i * 4096 + tid16);

    f32x4 A0 = ((rr[0] + rr[1]) + (rr[2] + rr[3])) + ((rr[4] + rr[5]) + (rr[6] + rr[7]));
    f32x4 B1 = rr[8] - rr[0];
    f32x4 B2 = rr[9] - rr[1];

    size_t s0 = (size_t)inp * 3145728 + (size_t)(b * 256 + t) * 3072 + tid * 4;
    *(uint2*)(A3 + s0)        = pack4v(A0);
    *(uint2*)(A3 + s0 + 1024) = pack4v(B1);
    *(uint2*)(A3 + s0 + 2048) = pack4v(B2);
}

// ====== launch 2: fused QKV GEMM + V^T pad, [1024 x 3072] @ Wt3_z^T + biasT ======
// blocks [0,768): 1-wave 64x64-tile GEMM (counted-vmcnt double-buffer, XCD swizzle)
// blocks [768,784): V^T pad rows 64..79 (row 64 = 1.0 softmax-l trick, rest 0)
__global__ __launch_bounds__(64) void gemm_qkv(
    const u16* __restrict__ A3, const u16* __restrict__ Wt3,
    const float* __restrict__ biasT,
    u16* __restrict__ qb, u16* __restrict__ kb, u16* __restrict__ vt)
{
    __shared__ __align__(16) u16 S[2][2][4096];   // [buf][A|B][64*64]

    const int lane = threadIdx.x;
    const int bid = blockIdx.x;

    if (bid >= 768) {
        // ---- vpad: 4 bh per block ----
        const int vb = bid - 768;                 // 0..15
        #pragma unroll
        for (int bh4 = 0; bh4 < 4; ++bh4) {
            const int bh = vb * 4 + bh4;
            #pragma unroll
            for (int it = 0; it < 8; ++it) {
                int gidx = it * 64 + lane;        // 512 uint4 per bh
                int row  = 64 + (gidx >> 5);
                int c0   = (gidx & 31) * 8;
                u32 fill = (row == 64) ? 0x3F803F80u : 0u;
                *(uint4*)(vt + (size_t)bh * 20480 + (size_t)row * 256 + c0) =
                    make_uint4(fill, fill, fill, fill);
            }
        }
        return;
    }

    const int mi   = lane & 15;
    const int quad = lane >> 4;

    const int wg  = (bid & 7) * 96 + (bid >> 3);  // bijective XCD chunking (768 = 8*96)
    const int z   = wg >> 8;
    const int m0  = ((wg >> 4) & 15) * 64;
    const int n0  = (wg & 15) * 64;

    const char* Ab = (const char*)(A3  + (size_t)z * 3145728) + (size_t)m0 * 6144;
    const char* Bb = (const char*)(Wt3 + (size_t)z * 3145728) + (size_t)n0 * 6144;

    f32x4 acc[4][4];
    #pragma unroll
    for (int i = 0; i < 4; ++i)
        #pragma unroll
        for (int j = 0; j < 4; ++j)
            acc[i][j] = (f32x4){0.f, 0.f, 0.f, 0.f};

    stage64(Ab, 0, S[0][0], lane, 6144);
    stage64(Bb, 0, S[0][1], lane, 6144);

    #pragma unroll 1
    for (int t = 0; t < 48; ++t) {
        const int cur = t & 1;
        if (t < 47) {
            stage64(Ab, (size_t)(t + 1) * 128, S[cur ^ 1][0], lane, 6144);
            stage64(Bb, (size_t)(t + 1) * 128, S[cur ^ 1][1], lane, 6144);
            asm volatile("s_waitcnt vmcnt(16)" ::: "memory");   // cur's 16 done, next 16 in flight
        } else {
            asm volatile("s_waitcnt vmcnt(0)" ::: "memory");
        }
        __builtin_amdgcn_sched_barrier(0);

        bf16x8 af[4][2], bf[4][2];
        frag_read(S[cur][0], mi, quad, af);
        frag_read(S[cur][1], mi, quad, bf);

        #pragma unroll
        for (int kc = 0; kc < 2; ++kc)
            #pragma unroll
            for (int i = 0; i < 4; ++i)
                #pragma unroll
                for (int j = 0; j < 4; ++j)
                    acc[i][j] = __builtin_amdgcn_mfma_f32_16x16x32_bf16(af[i][kc], bf[j][kc], acc[i][j], 0, 0, 0);
    }

    const float* bT = biasT + (size_t)z * 3072;
    if (z == 2) {
        #pragma unroll
        for (int j = 0; j < 4; ++j) {
            const int col = n0 + j * 16 + mi;
            const int h = col >> 6, d = col & 63;
            #pragma unroll
            for (int i = 0; i < 4; ++i) {
                const int row = m0 + i * 16 + quad * 4;
                const int b = row >> 8, t0 = row & 255;
                const int bh = b * 16 + h;
                u16 w[4];
                #pragma unroll
                for (int r = 0; r < 4; ++r) {
                    int t = t0 + r;
                    w[r] = f2bf(acc[i][j][r] + bT[(t < 2 ? t : 2) * 1024 + col]);
                }
                *(uint2*)(vt + (size_t)bh * 20480 + (size_t)d * 256 + t0) =
                    make_uint2((u32)w[0] | ((u32)w[1] << 16), (u32)w[2] | ((u32)w[3] << 16));
            }
        }
    } else {
        u16* dst = z ? kb : qb;
        #pragma unroll
        for (int j = 0; j < 4; ++j) {
            const int col = n0 + j * 16 + mi;
            const int h = col >> 6, d = col & 63;
            #pragma unroll
            for (int i = 0; i < 4; ++i) {
                const int row = m0 + i * 16 + quad * 4;
                const int b = row >> 8;
                const int bh = b * 16 + h;
                #pragma unroll
                for (int r = 0; r < 4; ++r) {
                    int t = (row & 255) + r;
                    dst[(((size_t)bh * 256 + t) << 6) + d] =
                        f2bf(acc[i][j][r] + bT[(t < 2 ? t : 2) * 1024 + col]);
                }
            }
        }
    }
}

// ---------------- launch 3: MFMA causal attention + fused up-dense ----------------
// One block per (qt, bh): 1 wave. After online attention, normalize -> G bf16 in P
// LDS -> MFMA against WupT + bup -> ms directly (updense kernel deleted).
__global__ __launch_bounds__(64) void attn_mfma(
    const u16* __restrict__ qb, const u16* __restrict__ kb,
    const u16* __restrict__ vt, const u16* __restrict__ WupT,
    const float* __restrict__ bup, u16* __restrict__ ms)
{
    __shared__ __align__(16) u16 P[64 * 72];    // stride 72 u16: 2-way banks only
    const int qt   = blockIdx.x;
    const int bh   = blockIdx.y;
    const int lane = threadIdx.x;
    const int mi   = lane & 15;
    const int quad = lane >> 4;

    const u16* Qb = qb + (((size_t)bh * 256 + qt * 64) << 6);
    const u16* Kb = kb + ((size_t)bh << 14);        // *256*64
    const u16* Vt = vt + (size_t)bh * 80 * 256;

    // Q fragments (persist across key tiles): A[m=mi][k=quad*8+j]
    bf16x8 qf[4][2];
    #pragma unroll
    for (int it = 0; it < 4; ++it)
        #pragma unroll
        for (int kc = 0; kc < 2; ++kc)
            qf[it][kc] = *(const bf16x8*)(Qb + ((it * 16 + mi) << 6) + kc * 32 + quad * 8);

    f32x4 o[4][5];
    #pragma unroll
    for (int it = 0; it < 4; ++it)
        #pragma unroll
        for (int jn = 0; jn < 5; ++jn)
            o[it][jn] = (f32x4){0.f, 0.f, 0.f, 0.f};

    for (int kt = 0; kt <= qt; ++kt) {
        // ---- S = Q @ K^T over this 64-key tile ----
        bf16x8 kf[4][2];
        #pragma unroll
        for (int jt = 0; jt < 4; ++jt)
            #pragma unroll
            for (int kc = 0; kc < 2; ++kc)
                kf[jt][kc] = *(const bf16x8*)(Kb + ((kt * 64 + jt * 16 + mi) << 6) + kc * 32 + quad * 8);

        f32x4 s[4][4];
        #pragma unroll
        for (int it = 0; it < 4; ++it)
            #pragma unroll
            for (int jt = 0; jt < 4; ++jt)
                s[it][jt] = (f32x4){0.f, 0.f, 0.f, 0.f};
        #pragma unroll
        for (int kc = 0; kc < 2; ++kc)
            #pragma unroll
            for (int it = 0; it < 4; ++it)
                #pragma unroll
                for (int jt = 0; jt < 4; ++jt)
                    s[it][jt] = __builtin_amdgcn_mfma_f32_16x16x32_bf16(qf[it][kc], kf[jt][kc], s[it][jt], 0, 0, 0);

        // ---- mask (diagonal tile only) + exp -> P (bf16, LDS, [row][key] stride 72) ----
        const bool diag = (kt == qt);
        #pragma unroll
        for (int it = 0; it < 4; ++it)
            #pragma unroll
            for (int jt = 0; jt < 4; ++jt)
                #pragma unroll
                for (int r = 0; r < 4; ++r) {
                    int qrow = it * 16 + quad * 4 + r;
                    int kcol = jt * 16 + mi;
                    float e = __expf(s[it][jt][r]);
                    if (diag && kcol > qrow) e = 0.f;
                    P[qrow * 72 + kcol] = f2bf(e);
                }

        // ---- PV: o += P @ [V | 1]^T  (A-frags from LDS, B-frags from V^T global) ----
        bf16x8 pf[4][2];
        #pragma unroll
        for (int it = 0; it < 4; ++it)
            #pragma unroll
            for (int kc = 0; kc < 2; ++kc)
                pf[it][kc] = *(const bf16x8*)(P + (it * 16 + mi) * 72 + kc * 32 + quad * 8);

        bf16x8 vf[5][2];
        #pragma unroll
        for (int jn = 0; jn < 5; ++jn)
            #pragma unroll
            for (int kc = 0; kc < 2; ++kc)
                vf[jn][kc] = *(const bf16x8*)(Vt + (size_t)(jn * 16 + mi) * 256 + kt * 64 + kc * 32 + quad * 8);

        #pragma unroll
        for (int kc = 0; kc < 2; ++kc)
            #pragma unroll
            for (int it = 0; it < 4; ++it)
                #pragma unroll
                for (int jn = 0; jn < 5; ++jn)
                    o[it][jn] = __builtin_amdgcn_mfma_f32_16x16x32_bf16(pf[it][kc], vf[jn][kc], o[it][jn], 0, 0, 0);
    }

    // ---- epilogue A: l sits in n-tile 4 (ones row of V^T); normalize -> G bf16 in P ----
    #pragma unroll
    for (int it = 0; it < 4; ++it) {
        float inv[4];
        #pragma unroll
        for (int r = 0; r < 4; ++r) {
            float lv = __shfl(o[it][4][r], (lane & 48));   // from lane quad*16+0
            inv[r] = 1.0f / lv;
        }
        #pragma unroll
        for (int jn = 0; jn < 4; ++jn)
            #pragma unroll
            for (int r = 0; r < 4; ++r) {
                int row = it * 16 + quad * 4 + r;
                P[row * 72 + jn * 16 + mi] = f2bf(o[it][jn][r] * inv[r]);
            }
    }
    // wave-private LDS: compiler inserts lgkmcnt before dependent reads; no barrier.

    // ---- epilogue B: up-dense R = G @ Wup via MFMA (B-frags = WupT rows) ----
    bf16x8 ga[4][2], wf[4][2];
    #pragma unroll
    for (int it = 0; it < 4; ++it)
        #pragma unroll
        for (int kc = 0; kc < 2; ++kc)
            ga[it][kc] = *(const bf16x8*)(P + (it * 16 + mi) * 72 + kc * 32 + quad * 8);
    #pragma unroll
    for (int jn = 0; jn < 4; ++jn)
        #pragma unroll
        for (int kc = 0; kc < 2; ++kc)
            wf[jn][kc] = *(const bf16x8*)(WupT + (jn * 16 + mi) * 64 + kc * 32 + quad * 8);

    f32x4 u[4][4];
    #pragma unroll
    for (int it = 0; it < 4; ++it)
        #pragma unroll
        for (int jn = 0; jn < 4; ++jn)
            u[it][jn] = (f32x4){0.f, 0.f, 0.f, 0.f};
    #pragma unroll
    for (int kc = 0; kc < 2; ++kc)
        #pragma unroll
        for (int it = 0; it < 4; ++it)
            #pragma unroll
            for (int jn = 0; jn < 4; ++jn)
                u[it][jn] = __builtin_amdgcn_mfma_f32_16x16x32_bf16(ga[it][kc], wf[jn][kc], u[it][jn], 0, 0, 0);

    // ---- write ms[(b*256 + m) * 1024 + h*64 + dp] ----
    const int b = bh >> 4, h = bh & 15;
    #pragma unroll
    for (int jn = 0; jn < 4; ++jn) {
        const int dp = jn * 16 + mi;
        const float bv = bup[dp];
        #pragma unroll
        for (int it = 0; it < 4; ++it)
            #pragma unroll
            for (int r = 0; r < 4; ++r) {
                int m = qt * 64 + it * 16 + quad * 4 + r;
                ms[((size_t)(b * 256 + m) << 10) + h * 64 + dp] = f2bf(u[it][jn][r] + bv);
            }
    }
}

// ====== launch 4: final dense + fused 8x upsample, straight into d_out ======
// 1-wave 64x64 pipelined GEMM (K=1024, 16 steps); C-tile staged to padded LDS,
// then 8x-replicated coalesced float4 stores (no intermediate C buffer).
__global__ __launch_bounds__(64) void gemm_out_up(
    const u16* __restrict__ A, const u16* __restrict__ Bt,
    const float* __restrict__ bias, float* __restrict__ out)
{
    __shared__ __align__(16) u16 S[2][2][4096];
    __shared__ __align__(16) float Cs[64][68];    // pad 68: 16B-aligned rows

    const int lane = threadIdx.x;
    const int mi   = lane & 15;
    const int quad = lane >> 4;

    const int bid = blockIdx.x;                   // 0..255
    const int wg  = (bid & 7) * 32 + (bid >> 3);  // bijective XCD chunking (256 = 8*32)
    const int m0  = (wg >> 4) * 64;
    const int n0  = (wg & 15) * 64;

    const char* Ab = (const char*)A  + (size_t)m0 * 2048;
    const char* Bb = (const char*)Bt + (size_t)n0 * 2048;

    f32x4 acc[4][4];
    #pragma unroll
    for (int i = 0; i < 4; ++i)
        #pragma unroll
        for (int j = 0; j < 4; ++j)
            acc[i][j] = (f32x4){0.f, 0.f, 0.f, 0.f};

    stage64(Ab, 0, S[0][0], lane, 2048);
    stage64(Bb, 0, S[0][1], lane, 2048);

    #pragma unroll 1
    for (int t = 0; t < 16; ++t) {
        const int cur = t & 1;
        if (t < 15) {
            stage64(Ab, (size_t)(t + 1) * 128, S[cur ^ 1][0], lane, 2048);
            stage64(Bb, (size_t)(t + 1) * 128, S[cur ^ 1][1], lane, 2048);
            asm volatile("s_waitcnt vmcnt(16)" ::: "memory");
        } else {
            asm volatile("s_waitcnt vmcnt(0)" ::: "memory");
        }
        __builtin_amdgcn_sched_barrier(0);

        bf16x8 af[4][2], bf[4][2];
        frag_read(S[cur][0], mi, quad, af);
        frag_read(S[cur][1], mi, quad, bf);

        #pragma unroll
        for (int kc = 0; kc < 2; ++kc)
            #pragma unroll
            for (int i = 0; i < 4; ++i)
                #pragma unroll
                for (int j = 0; j < 4; ++j)
                    acc[i][j] = __builtin_amdgcn_mfma_f32_16x16x32_bf16(af[i][kc], bf[j][kc], acc[i][j], 0, 0, 0);
    }

    // C-tile (+bias) to LDS
    #pragma unroll
    for (int j = 0; j < 4; ++j) {
        const float bv = bias[n0 + j * 16 + mi];
        #pragma unroll
        for (int i = 0; i < 4; ++i)
            #pragma unroll
            for (int r = 0; r < 4; ++r)
                Cs[i * 16 + quad * 4 + r][j * 16 + mi] = acc[i][j][r] + bv;
    }

    // 8x broadcast write-out: 64 C-rows x 8 reps x 64 cols = 8192 float4
    // per iter: all lanes share one C-row (broadcast LDS read), 4 reps x 16 col4.
    const int col4 = lane & 15;
    #pragma unroll 4
    for (int it = 0; it < 128; ++it) {
        const int crow = it >> 1;
        const int rep  = ((it & 1) << 2) + (lane >> 4);
        float4 val = *(const float4*)&Cs[crow][col4 * 4];
        const int R = m0 + crow;
        const int b = R >> 8, tc = R & 255;
        float* po = out + (((size_t)((b << 11) + (tc << 3) + rep)) << 10) + n0 + (col4 << 2);
        *(float4*)po = val;
    }
}

extern "C" void kernel_launch(void* const* d_in, const int* in_sizes, int n_in,
                              void* d_out, int out_size, void* d_ws, size_t ws_size,
                              hipStream_t stream) {
    const float* q   = (const float*)d_in[0];
    const float* k   = (const float*)d_in[1];
    const float* v   = (const float*)d_in[2];
    const float* Wq  = (const float*)d_in[3];
    const float* bq  = (const float*)d_in[4];
    const float* Wk  = (const float*)d_in[5];
    const float* bk  = (const float*)d_in[6];
    const float* Wv  = (const float*)d_in[7];
    const float* bv  = (const float*)d_in[8];
    const float* Wup = (const float*)d_in[9];
    const float* bup = (const float*)d_in[10];
    const float* Wc  = (const float*)d_in[11];
    const float* bc  = (const float*)d_in[12];
    const float* wcq = (const float*)d_in[13];
    const float* bcq = (const float*)d_in[14];
    const float* wck = (const float*)d_in[15];
    const float* bck = (const float*)d_in[16];
    const float* wcv = (const float*)d_in[17];
    const float* bcv = (const float*)d_in[18];

    // A3 staging (18.9 MB bf16 [3][1024][3072]) lives in d_out; gemm_out_up
    // rewrites all of d_out at the end.
    u16* A3 = (u16*)d_out;

    char* wsb = (char*)d_ws;
    // ws layout (bytes):
    //   0        : Wt3  bf16 [3][1024 n][3072 k]  18,874,368
    //   18874368 : Wtc  bf16 [1024][1024]          2,097,152
    //   20971520 : biasT f32 [3][3][1024]             36,864
    //   21008384 : qb   bf16 [64*256][64]          2,097,152
    //   23105536 : kb   bf16 [64*256][64]          2,097,152
    //   25202688 : vt   bf16 [64][80][256]         2,621,440
    //   27824128 : WupT bf16 [64][64]                  8,192
    //   32018432 : ms   bf16 [1024][1024]          2,097,152
    u16*   Wt3   = (u16*)wsb;
    u16*   Wtc   = (u16*)(wsb + 18874368);
    float* biasT = (float*)(wsb + 20971520);
    u16*   qb    = (u16*)(wsb + 21008384);
    u16*   kb    = (u16*)(wsb + 23105536);
    u16*   vt    = (u16*)(wsb + 25202688);
    u16*   WupT  = (u16*)(wsb + 27824128);
    u16*   ms    = (u16*)(wsb + 32018432);

    // 1. weight prep + bias table + WupT + input staging (one dispatch)
    prep_stage<<<4109, 256, 0, stream>>>(q, k, v, Wq, Wk, Wv, Wc, Wup,
                                         wcq, wck, wcv, bcq, bck, bcv,
                                         bq, bk, bv, Wt3, Wtc, biasT, WupT, A3);
    // 2. fused QKV GEMM + V^T pad (784 one-wave blocks)
    gemm_qkv<<<784, 64, 0, stream>>>(A3, Wt3, biasT, qb, kb, vt);
    // 3. MFMA causal attention + fused up-dense -> ms (256 one-wave blocks)
    attn_mfma<<<dim3(4, 64), 64, 0, stream>>>(qb, kb, vt, WupT, bup, ms);
    // 4. final dense + fused 8x upsample -> d_out (256 one-wave blocks)
    gemm_out_up<<<256, 64, 0, stream>>>(ms, Wtc, bc, (float*)d_out);
}